// Round 13
// baseline (206.159 us; speedup 1.0000x reference)
//
#include <hip/hip_runtime.h>
#include <hip/hip_fp16.h>
#include <math.h>

#define N_NODES 12000
#define C 128
#define NEDGE 192000
#define BW 384  // u32 words per LDS dedup bitset (12288 bits >= 12000)

// acc_lo += (float)f16_lo(u); acc_hi += (float)f16_hi(u)  -- one VOP3P each
__device__ __forceinline__ void fmix2(float& lo, float& hi, unsigned u, float one) {
    asm("v_fma_mix_f32 %0, %2, %3, %0 op_sel:[0,0,0] op_sel_hi:[1,0,0]\n\t"
        "v_fma_mix_f32 %1, %2, %3, %1 op_sel:[1,0,0] op_sel_hi:[1,0,0]"
        : "+v"(lo), "+v"(hi)
        : "v"(u), "v"(one));
}

#define ACCM(p, u)                                            \
    fmix2(p##0, p##1, u.x, one); fmix2(p##2, p##3, u.y, one); \
    fmix2(p##4, p##5, u.z, one); fmix2(p##6, p##7, u.w, one)

#define RED2(x) x += __shfl_xor(x, 16); x += __shfl_xor(x, 32)

// ---- merged: x->f16 + degree hist (blocks 0..2999) | weight fusion (blocks 3000..3127) ----
// Wf1[j][c] = sum_k W1[j][k]*Wg[k][c]; bfused[c] = b1@Wg_top + b2@Wg_bot + bg
__global__ __launch_bounds__(256) void prep_fuse(const float* __restrict__ x,
                                                 unsigned* __restrict__ xbu,
                                                 const int* __restrict__ ei,
                                                 int* __restrict__ deg,
                                                 const float* __restrict__ W1,
                                                 const float* __restrict__ W2,
                                                 const float* __restrict__ Wg,
                                                 const float* __restrict__ b1,
                                                 const float* __restrict__ b2,
                                                 const float* __restrict__ bg,
                                                 float* __restrict__ Wf1,
                                                 float* __restrict__ Wf2,
                                                 float* __restrict__ bfused) {
    const int tid = threadIdx.x;
    if (blockIdx.x < 3000) {
        int g = blockIdx.x * 256 + tid;
        if (g < N_NODES * C / 2) {
            unsigned pa = __half_as_ushort(__float2half(x[2 * g]));
            unsigned pb = __half_as_ushort(__float2half(x[2 * g + 1]));
            xbu[g] = pa | (pb << 16);
        }
        if (g < NEDGE) atomicAdd(&deg[ei[g]], 1);
        return;
    }
    __shared__ __align__(16) float wg1[C];
    __shared__ __align__(16) float wg2[C];
    __shared__ float sb[C];
    const int c = blockIdx.x - 3000;
    const int j = tid;
    if (j < 128) {
        float g1 = Wg[(size_t)j * C + c];
        float g2 = Wg[(size_t)(C + j) * C + c];
        wg1[j] = g1;
        wg2[j] = g2;
        sb[j] = b1[j] * g1 + b2[j] * g2;
    }
    __syncthreads();
    if (j < 128) {
        float s1 = 0.f, s2 = 0.f;
        for (int k = 0; k < C; k += 4) {
            float4 a = *(const float4*)&W1[(size_t)j * C + k];
            float4 b = *(const float4*)&W2[(size_t)j * C + k];
            float4 u = *(const float4*)&wg1[k];
            float4 v = *(const float4*)&wg2[k];
            s1 += a.x * u.x + a.y * u.y + a.z * u.z + a.w * u.w;
            s2 += b.x * v.x + b.y * v.y + b.z * v.z + b.w * v.w;
        }
        Wf1[(size_t)j * C + c] = s1;  // [k][c] layout, same as W1
        Wf2[(size_t)j * C + c] = s2;
        if (j == 0) {
            float s = bg[c];
            for (int k = 0; k < C; ++k) s += sb[k];
            bfused[c] = s;
        }
    }
}

// ---- exclusive scan of degrees -> CSR offsets (single 1024-thread block) ----
__global__ __launch_bounds__(1024) void scan_offsets(const int* __restrict__ deg,
                                                     int* __restrict__ off) {
    __shared__ int wsum[16];
    const int t = threadIdx.x;
    const int lane = t & 63, wv = t >> 6;
    const int PER = 12;  // 1024*12 = 12288 >= 12000
    const int lo = t * PER;
    int local[PER];
    int sum = 0;
#pragma unroll
    for (int k = 0; k < PER; ++k) {
        int i = lo + k;
        int d = (i < N_NODES) ? deg[i] : 0;
        local[k] = sum;
        sum += d;
    }
    int p = sum;
    for (int d = 1; d < 64; d <<= 1) {
        int u = __shfl_up(p, d);
        if (lane >= d) p += u;
    }
    if (lane == 63) wsum[wv] = p;
    __syncthreads();
    int wbase = 0;
    for (int k = 0; k < wv; ++k) wbase += wsum[k];
    const int tbase = wbase + p - sum;
#pragma unroll
    for (int k = 0; k < PER; ++k) {
        int i = lo + k;
        if (i < N_NODES) off[i] = tbase + local[k];
    }
    if (t == 0) off[N_NODES] = NEDGE;
}

// ---- fill CSR columns (order within row irrelevant; duplicates kept) ----
__global__ void fill_csr(const int* __restrict__ ei, const int* __restrict__ off,
                         int* __restrict__ cur, int* __restrict__ col) {
    int e = blockIdx.x * blockDim.x + threadIdx.x;
    if (e >= NEDGE) return;
    int s = ei[e];
    int t = ei[NEDGE + e];
    int pos = atomicAdd(&cur[s], 1);
    col[off[s] + pos] = t;
}

// ---- fused: agg1 (f16 CSR gather) + flattened 2-hop union + list gather ----
// (verbatim round-8 kernel: 71 us, verified)
__global__ __launch_bounds__(256) void twohop_fused(const int* __restrict__ off,
                                                    const int* __restrict__ col,
                                                    const unsigned* __restrict__ xb,
                                                    float* __restrict__ agg1,
                                                    float* __restrict__ agg2) {
    __shared__ unsigned acc[BW];          // 1.5 KB dedup bitset
    __shared__ int sjb[64];
    __shared__ int spos[64];
    __shared__ int stot;
    __shared__ int wtot[2];
    __shared__ unsigned short lst[4096];  // 8 KB; chunk cap = 128 words * 32 bits
    __shared__ float red[4][256];         // 4 KB
    const int i = blockIdx.x;
    const int tid = threadIdx.x;
    const int lane = tid & 63;
    const int wv = tid >> 6;
    const int grp = tid >> 4, l16 = tid & 15;
    const int rowbeg = off[i], rowend = off[i + 1];
    const uint4* xb4 = (const uint4*)xb;
    const float one = 1.0f;

    for (int w = tid; w < BW; w += 256) acc[w] = 0u;
    __syncthreads();  // acc ready for atomics

    // ---- 2-hop union, flattened per 64-neighbor chunk ----
    for (int base = rowbeg; base < rowend; base += 64) {
        int d = rowend - base;
        if (d > 64) d = 64;
        if (tid < 64) {
            int len = 0;
            if (tid < d) {
                int j = col[base + tid];
                int jb = off[j];
                len = off[j + 1] - jb;
                sjb[tid] = jb;
            }
            int p = len;
            for (int dd = 1; dd < 64; dd <<= 1) {
                int u = __shfl_up(p, dd);
                if (lane >= dd) p += u;
            }
            spos[tid] = p - len;  // exclusive
            if (tid == 63) stot = p;
        }
        __syncthreads();
        const int total = stot;
        for (int q = tid; q < total; q += 256) {
            int lo = 0, hi = d - 1;  // largest k with spos[k] <= q
            while (lo < hi) {
                int mid = (lo + hi + 1) >> 1;
                if (spos[mid] <= q) lo = mid; else hi = mid - 1;
            }
            int t = col[sjb[lo] + (q - spos[lo])];
            atomicOr(&acc[t >> 5], 1u << (t & 31));
        }
        __syncthreads();
    }
    if (tid == 0) acc[i >> 5] &= ~(1u << (i & 31));  // zero diagonal

    // ---- agg1: f16 counted gather over own row (multiplicity kept), 2x unrolled ----
    float b0 = 0, b1 = 0, b2 = 0, b3 = 0, b4 = 0, b5 = 0, b6 = 0, b7 = 0;
    {
        int idx = rowbeg + grp;
        for (; idx + 16 < rowend; idx += 32) {
            int k0 = col[idx], k1 = col[idx + 16];
            uint4 u0 = xb4[(unsigned)((k0 << 4) | l16)];
            uint4 u1 = xb4[(unsigned)((k1 << 4) | l16)];
            ACCM(b, u0);
            ACCM(b, u1);
        }
        if (idx < rowend) {
            int k0 = col[idx];
            uint4 u0 = xb4[(unsigned)((k0 << 4) | l16)];
            ACCM(b, u0);
        }
    }

    // ---- agg2: per-chunk enumerate (prefix-scan) + counted gather, 4x unrolled ----
    float a0 = 0, a1 = 0, a2 = 0, a3 = 0, a4 = 0, a5 = 0, a6 = 0, a7 = 0;
    for (int chunk = 0; chunk < 3; ++chunk) {
        __syncthreads();  // chunk 0: diag clear visible; others: lst consumed
        unsigned v = 0;
        int n = 0, p = 0;
        if (tid < 128) {
            v = acc[chunk * 128 + tid];
            n = __popc(v);
            p = n;
            for (int dd = 1; dd < 64; dd <<= 1) {
                int u = __shfl_up(p, dd);
                if (lane >= dd) p += u;
            }
            if (lane == 63) wtot[wv] = p;
        }
        __syncthreads();
        if (tid < 128) {
            int o = ((wv == 1) ? wtot[0] : 0) + p - n;
            int wbase = (chunk * 128 + tid) << 5;
            while (v) {
                int b = __ffs(v) - 1;
                v &= v - 1;
                lst[o++] = (unsigned short)(wbase + b);
            }
        }
        __syncthreads();
        const int total = wtot[0] + wtot[1];
        int q = grp;
        for (; q + 48 < total; q += 64) {
            int k0 = lst[q], k1 = lst[q + 16], k2 = lst[q + 32], k3 = lst[q + 48];
            uint4 u0 = xb4[(unsigned)((k0 << 4) | l16)];
            uint4 u1 = xb4[(unsigned)((k1 << 4) | l16)];
            uint4 u2 = xb4[(unsigned)((k2 << 4) | l16)];
            uint4 u3 = xb4[(unsigned)((k3 << 4) | l16)];
            ACCM(a, u0);
            ACCM(a, u1);
            ACCM(a, u2);
            ACCM(a, u3);
        }
        for (; q + 16 < total; q += 32) {
            int k0 = lst[q], k1 = lst[q + 16];
            uint4 u0 = xb4[(unsigned)((k0 << 4) | l16)];
            uint4 u1 = xb4[(unsigned)((k1 << 4) | l16)];
            ACCM(a, u0);
            ACCM(a, u1);
        }
        if (q < total) {
            int k0 = lst[q];
            uint4 u0 = xb4[(unsigned)((k0 << 4) | l16)];
            ACCM(a, u0);
        }
    }

    // ---- cross-group reduction: shuffle within wave, then 4-wave LDS combine ----
    RED2(a0); RED2(a1); RED2(a2); RED2(a3); RED2(a4); RED2(a5); RED2(a6); RED2(a7);
    RED2(b0); RED2(b1); RED2(b2); RED2(b3); RED2(b4); RED2(b5); RED2(b6); RED2(b7);
    __syncthreads();
    if (lane < 16) {
        red[wv][l16 * 8 + 0] = a0; red[wv][l16 * 8 + 1] = a1;
        red[wv][l16 * 8 + 2] = a2; red[wv][l16 * 8 + 3] = a3;
        red[wv][l16 * 8 + 4] = a4; red[wv][l16 * 8 + 5] = a5;
        red[wv][l16 * 8 + 6] = a6; red[wv][l16 * 8 + 7] = a7;
        red[wv][128 + l16 * 8 + 0] = b0; red[wv][128 + l16 * 8 + 1] = b1;
        red[wv][128 + l16 * 8 + 2] = b2; red[wv][128 + l16 * 8 + 3] = b3;
        red[wv][128 + l16 * 8 + 4] = b4; red[wv][128 + l16 * 8 + 5] = b5;
        red[wv][128 + l16 * 8 + 6] = b6; red[wv][128 + l16 * 8 + 7] = b7;
    }
    __syncthreads();
    float s = red[0][tid] + red[1][tid] + red[2][tid] + red[3][tid];
    if (tid < 128) agg2[(size_t)i * C + tid] = s;
    else           agg1[(size_t)i * C + (tid - 128)] = s;
}

// ---- single-pass epilogue: 8 rows/block (1500 blocks), 2 cols x 2 rows/thread ----
// z1,z2,gate logits in ONE k-loop; coalesced float2 weight reads; 1 barrier.
__global__ __launch_bounds__(256) void epilogue(const float* __restrict__ agg1,
                                                const float* __restrict__ agg2,
                                                const float* __restrict__ W1,
                                                const float* __restrict__ W2,
                                                const float* __restrict__ Wf1,
                                                const float* __restrict__ Wf2,
                                                const float* __restrict__ b1,
                                                const float* __restrict__ b2,
                                                const float* __restrict__ bfused,
                                                float* __restrict__ out) {
    __shared__ float sA[8][C];  // 4 KB
    __shared__ float sB[8][C];  // 4 KB
    const int r0 = blockIdx.x * 8;
    const int tid = threadIdx.x;
    const int c0 = (tid & 63) * 2;   // columns c0, c0+1
    const int rg = (tid >> 6) * 2;   // 2 rows per thread

    for (int idx = tid; idx < 8 * C / 4; idx += 256) {  // one float4 per thread
        int r = idx >> 5, k4 = idx & 31;
        ((float4*)sA[r])[k4] = ((const float4*)&agg1[(size_t)(r0 + r) * C])[k4];
        ((float4*)sB[r])[k4] = ((const float4*)&agg2[(size_t)(r0 + r) * C])[k4];
    }
    __syncthreads();

    float z1v[2][2] = {}, z2v[2][2] = {}, gv[2][2] = {};
    for (int k = 0; k < C; k += 4) {
        float2 w1q[4], w2q[4], f1q[4], f2q[4];
#pragma unroll
        for (int kk = 0; kk < 4; ++kk) {
            w1q[kk] = *(const float2*)&W1[(size_t)(k + kk) * C + c0];
            w2q[kk] = *(const float2*)&W2[(size_t)(k + kk) * C + c0];
            f1q[kk] = *(const float2*)&Wf1[(size_t)(k + kk) * C + c0];
            f2q[kk] = *(const float2*)&Wf2[(size_t)(k + kk) * C + c0];
        }
#pragma unroll
        for (int r = 0; r < 2; ++r) {
            float4 a4 = *(const float4*)&sA[rg + r][k];
            float4 b4 = *(const float4*)&sB[rg + r][k];
            float av[4] = {a4.x, a4.y, a4.z, a4.w};
            float bv[4] = {b4.x, b4.y, b4.z, b4.w};
#pragma unroll
            for (int kk = 0; kk < 4; ++kk) {
                z1v[r][0] += av[kk] * w1q[kk].x;  z1v[r][1] += av[kk] * w1q[kk].y;
                z2v[r][0] += bv[kk] * w2q[kk].x;  z2v[r][1] += bv[kk] * w2q[kk].y;
                gv[r][0]  += av[kk] * f1q[kk].x + bv[kk] * f2q[kk].x;
                gv[r][1]  += av[kk] * f1q[kk].y + bv[kk] * f2q[kk].y;
            }
        }
    }
    const float2 b1v = *(const float2*)&b1[c0];
    const float2 b2v = *(const float2*)&b2[c0];
    const float2 bfv = *(const float2*)&bfused[c0];
#pragma unroll
    for (int r = 0; r < 2; ++r) {
        float g0 = 1.f / (1.f + expf(-(gv[r][0] + bfv.x)));
        float g1 = 1.f / (1.f + expf(-(gv[r][1] + bfv.y)));
        float2 res;
        res.x = g0 * (z1v[r][0] + b1v.x) + (1.f - g0) * (z2v[r][0] + b2v.x);
        res.y = g1 * (z1v[r][1] + b1v.y) + (1.f - g1) * (z2v[r][1] + b2v.y);
        *(float2*)&out[(size_t)(r0 + rg + r) * C + c0] = res;
    }
}

extern "C" void kernel_launch(void* const* d_in, const int* in_sizes, int n_in,
                              void* d_out, int out_size, void* d_ws, size_t ws_size,
                              hipStream_t stream) {
    const float* x  = (const float*)d_in[0];
    const int*   ei = (const int*)d_in[1];
    const float* W1 = (const float*)d_in[2];
    const float* b1 = (const float*)d_in[3];
    const float* W2 = (const float*)d_in[4];
    const float* b2 = (const float*)d_in[5];
    const float* Wg = (const float*)d_in[6];
    const float* bg = (const float*)d_in[7];
    float* out = (float*)d_out;

    char* ws = (char*)d_ws;
    size_t o = 0;
    auto alloc = [&](size_t bytes) { char* p = ws + o; o = (o + bytes + 255) & ~(size_t)255; return p; };
    int* col      = (int*)alloc((size_t)NEDGE * 4);
    int* deg      = (int*)alloc((size_t)N_NODES * 2 * 4);   // deg + cur contiguous
    int* cur      = deg + N_NODES;
    int* off      = (int*)alloc((size_t)(N_NODES + 1) * 4);
    unsigned* xb  = (unsigned*)alloc((size_t)N_NODES * C * 2);  // f16 x
    float* agg1   = (float*)alloc((size_t)N_NODES * C * 4);
    float* agg2   = (float*)alloc((size_t)N_NODES * C * 4);
    float* Wf1    = (float*)alloc((size_t)C * C * 4);
    float* Wf2    = (float*)alloc((size_t)C * C * 4);
    float* bfused = (float*)alloc((size_t)C * 4);
    // total ~16.5 MB (proven safe)

    hipMemsetAsync(deg, 0, (size_t)N_NODES * 2 * 4, stream);

    prep_fuse<<<3128, 256, 0, stream>>>(x, xb, ei, deg, W1, W2, Wg, b1, b2, bg, Wf1, Wf2, bfused);
    scan_offsets<<<1, 1024, 0, stream>>>(deg, off);
    fill_csr<<<(NEDGE + 255) / 256, 256, 0, stream>>>(ei, off, cur, col);
    twohop_fused<<<N_NODES, 256, 0, stream>>>(off, col, xb, agg1, agg2);
    epilogue<<<N_NODES / 8, 256, 0, stream>>>(agg1, agg2, W1, W2, Wf1, Wf2, b1, b2, bfused, out);
}

// Round 14
// 149.562 us; speedup vs baseline: 1.3784x; 1.3784x over previous
//
#include <hip/hip_runtime.h>
#include <hip/hip_fp16.h>
#include <math.h>

#define N_NODES 12000
#define C 128
#define NEDGE 192000
#define BW 384  // u32 words per LDS dedup bitset (12288 bits >= 12000)

// acc_lo += (float)f16_lo(u); acc_hi += (float)f16_hi(u)  -- one VOP3P each
__device__ __forceinline__ void fmix2(float& lo, float& hi, unsigned u, float one) {
    asm("v_fma_mix_f32 %0, %2, %3, %0 op_sel:[0,0,0] op_sel_hi:[1,0,0]\n\t"
        "v_fma_mix_f32 %1, %2, %3, %1 op_sel:[1,0,0] op_sel_hi:[1,0,0]"
        : "+v"(lo), "+v"(hi)
        : "v"(u), "v"(one));
}

// acc += a.lo*b.lo + a.hi*b.hi  (f16 pairs, f32 accumulate) -- one VOP3P
__device__ __forceinline__ void dot2acc(float& acc, unsigned a, unsigned b) {
    asm("v_dot2_f32_f16 %0, %1, %2, %0" : "+v"(acc) : "v"(a), "v"(b));
}

__device__ __forceinline__ unsigned packh2(float lo, float hi) {
    __half2 h = __floats2half2_rn(lo, hi);
    return *reinterpret_cast<unsigned*>(&h);
}

#define ACCM(p, u)                                            \
    fmix2(p##0, p##1, u.x, one); fmix2(p##2, p##3, u.y, one); \
    fmix2(p##4, p##5, u.z, one); fmix2(p##6, p##7, u.w, one)

#define RED2(x) x += __shfl_xor(x, 16); x += __shfl_xor(x, 32)

// ---- merged: x->f16 + degree hist (blocks 0..2999) | weight fuse+pack (blocks 3000..3127) ----
__global__ __launch_bounds__(256) void prep_fuse(const float* __restrict__ x,
                                                 unsigned* __restrict__ xbu,
                                                 const int* __restrict__ ei,
                                                 int* __restrict__ deg,
                                                 const float* __restrict__ W1,
                                                 const float* __restrict__ W2,
                                                 const float* __restrict__ Wg,
                                                 const float* __restrict__ b1,
                                                 const float* __restrict__ b2,
                                                 const float* __restrict__ bg,
                                                 unsigned* __restrict__ Wp1,
                                                 unsigned* __restrict__ Wp2,
                                                 unsigned* __restrict__ Wpf1,
                                                 unsigned* __restrict__ Wpf2,
                                                 float* __restrict__ bfused) {
    const int tid = threadIdx.x;
    if (blockIdx.x < 3000) {
        int g = blockIdx.x * 256 + tid;
        if (g < N_NODES * C / 2) {
            unsigned pa = __half_as_ushort(__float2half(x[2 * g]));
            unsigned pb = __half_as_ushort(__float2half(x[2 * g + 1]));
            xbu[g] = pa | (pb << 16);
        }
        if (g < NEDGE) atomicAdd(&deg[ei[g]], 1);
        return;
    }
    __shared__ __align__(16) float wg1[C];
    __shared__ __align__(16) float wg2[C];
    __shared__ float sb[C];
    __shared__ float l1[C], l2[C], lf1[C], lf2[C];
    const int c = blockIdx.x - 3000;
    const int j = tid;
    if (j < 128) {
        float g1 = Wg[(size_t)j * C + c];
        float g2 = Wg[(size_t)(C + j) * C + c];
        wg1[j] = g1;
        wg2[j] = g2;
        sb[j] = b1[j] * g1 + b2[j] * g2;
    }
    __syncthreads();
    if (j < 128) {
        float s1 = 0.f, s2 = 0.f;
        for (int k = 0; k < C; k += 4) {
            float4 a = *(const float4*)&W1[(size_t)j * C + k];
            float4 b = *(const float4*)&W2[(size_t)j * C + k];
            float4 u = *(const float4*)&wg1[k];
            float4 v = *(const float4*)&wg2[k];
            s1 += a.x * u.x + a.y * u.y + a.z * u.z + a.w * u.w;
            s2 += b.x * v.x + b.y * v.y + b.z * v.z + b.w * v.w;
        }
        l1[j] = W1[(size_t)j * C + c];
        l2[j] = W2[(size_t)j * C + c];
        lf1[j] = s1;  // Wf1[j][c]
        lf2[j] = s2;
    }
    __syncthreads();
    if (j < 64) {  // pack k-pairs (2j, 2j+1) for column c
        Wp1[(size_t)j * C + c]  = packh2(l1[2 * j], l1[2 * j + 1]);
        Wp2[(size_t)j * C + c]  = packh2(l2[2 * j], l2[2 * j + 1]);
        Wpf1[(size_t)j * C + c] = packh2(lf1[2 * j], lf1[2 * j + 1]);
        Wpf2[(size_t)j * C + c] = packh2(lf2[2 * j], lf2[2 * j + 1]);
    }
    if (j == 0) {
        float s = bg[c];
        for (int k = 0; k < C; ++k) s += sb[k];
        bfused[c] = s;
    }
}

// ---- exclusive scan of degrees -> CSR offsets (single 1024-thread block) ----
__global__ __launch_bounds__(1024) void scan_offsets(const int* __restrict__ deg,
                                                     int* __restrict__ off) {
    __shared__ int wsum[16];
    const int t = threadIdx.x;
    const int lane = t & 63, wv = t >> 6;
    const int PER = 12;  // 1024*12 = 12288 >= 12000
    const int lo = t * PER;
    int local[PER];
    int sum = 0;
#pragma unroll
    for (int k = 0; k < PER; ++k) {
        int i = lo + k;
        int d = (i < N_NODES) ? deg[i] : 0;
        local[k] = sum;
        sum += d;
    }
    int p = sum;
    for (int d = 1; d < 64; d <<= 1) {
        int u = __shfl_up(p, d);
        if (lane >= d) p += u;
    }
    if (lane == 63) wsum[wv] = p;
    __syncthreads();
    int wbase = 0;
    for (int k = 0; k < wv; ++k) wbase += wsum[k];
    const int tbase = wbase + p - sum;
#pragma unroll
    for (int k = 0; k < PER; ++k) {
        int i = lo + k;
        if (i < N_NODES) off[i] = tbase + local[k];
    }
    if (t == 0) off[N_NODES] = NEDGE;
}

// ---- fill CSR columns (order within row irrelevant; duplicates kept) ----
__global__ void fill_csr(const int* __restrict__ ei, const int* __restrict__ off,
                         int* __restrict__ cur, int* __restrict__ col) {
    int e = blockIdx.x * blockDim.x + threadIdx.x;
    if (e >= NEDGE) return;
    int s = ei[e];
    int t = ei[NEDGE + e];
    int pos = atomicAdd(&cur[s], 1);
    col[off[s] + pos] = t;
}

// ---- fused: agg1 (f16 CSR gather) + flattened 2-hop union + list gather ----
// (verbatim round-8 kernel: 71 us, verified)
__global__ __launch_bounds__(256) void twohop_fused(const int* __restrict__ off,
                                                    const int* __restrict__ col,
                                                    const unsigned* __restrict__ xb,
                                                    float* __restrict__ agg1,
                                                    float* __restrict__ agg2) {
    __shared__ unsigned acc[BW];          // 1.5 KB dedup bitset
    __shared__ int sjb[64];
    __shared__ int spos[64];
    __shared__ int stot;
    __shared__ int wtot[2];
    __shared__ unsigned short lst[4096];  // 8 KB; chunk cap = 128 words * 32 bits
    __shared__ float red[4][256];         // 4 KB
    const int i = blockIdx.x;
    const int tid = threadIdx.x;
    const int lane = tid & 63;
    const int wv = tid >> 6;
    const int grp = tid >> 4, l16 = tid & 15;
    const int rowbeg = off[i], rowend = off[i + 1];
    const uint4* xb4 = (const uint4*)xb;
    const float one = 1.0f;

    for (int w = tid; w < BW; w += 256) acc[w] = 0u;
    __syncthreads();  // acc ready for atomics

    // ---- 2-hop union, flattened per 64-neighbor chunk ----
    for (int base = rowbeg; base < rowend; base += 64) {
        int d = rowend - base;
        if (d > 64) d = 64;
        if (tid < 64) {
            int len = 0;
            if (tid < d) {
                int j = col[base + tid];
                int jb = off[j];
                len = off[j + 1] - jb;
                sjb[tid] = jb;
            }
            int p = len;
            for (int dd = 1; dd < 64; dd <<= 1) {
                int u = __shfl_up(p, dd);
                if (lane >= dd) p += u;
            }
            spos[tid] = p - len;  // exclusive
            if (tid == 63) stot = p;
        }
        __syncthreads();
        const int total = stot;
        for (int q = tid; q < total; q += 256) {
            int lo = 0, hi = d - 1;  // largest k with spos[k] <= q
            while (lo < hi) {
                int mid = (lo + hi + 1) >> 1;
                if (spos[mid] <= q) lo = mid; else hi = mid - 1;
            }
            int t = col[sjb[lo] + (q - spos[lo])];
            atomicOr(&acc[t >> 5], 1u << (t & 31));
        }
        __syncthreads();
    }
    if (tid == 0) acc[i >> 5] &= ~(1u << (i & 31));  // zero diagonal

    // ---- agg1: f16 counted gather over own row (multiplicity kept), 2x unrolled ----
    float b0 = 0, b1 = 0, b2 = 0, b3 = 0, b4 = 0, b5 = 0, b6 = 0, b7 = 0;
    {
        int idx = rowbeg + grp;
        for (; idx + 16 < rowend; idx += 32) {
            int k0 = col[idx], k1 = col[idx + 16];
            uint4 u0 = xb4[(unsigned)((k0 << 4) | l16)];
            uint4 u1 = xb4[(unsigned)((k1 << 4) | l16)];
            ACCM(b, u0);
            ACCM(b, u1);
        }
        if (idx < rowend) {
            int k0 = col[idx];
            uint4 u0 = xb4[(unsigned)((k0 << 4) | l16)];
            ACCM(b, u0);
        }
    }

    // ---- agg2: per-chunk enumerate (prefix-scan) + counted gather, 4x unrolled ----
    float a0 = 0, a1 = 0, a2 = 0, a3 = 0, a4 = 0, a5 = 0, a6 = 0, a7 = 0;
    for (int chunk = 0; chunk < 3; ++chunk) {
        __syncthreads();  // chunk 0: diag clear visible; others: lst consumed
        unsigned v = 0;
        int n = 0, p = 0;
        if (tid < 128) {
            v = acc[chunk * 128 + tid];
            n = __popc(v);
            p = n;
            for (int dd = 1; dd < 64; dd <<= 1) {
                int u = __shfl_up(p, dd);
                if (lane >= dd) p += u;
            }
            if (lane == 63) wtot[wv] = p;
        }
        __syncthreads();
        if (tid < 128) {
            int o = ((wv == 1) ? wtot[0] : 0) + p - n;
            int wbase = (chunk * 128 + tid) << 5;
            while (v) {
                int b = __ffs(v) - 1;
                v &= v - 1;
                lst[o++] = (unsigned short)(wbase + b);
            }
        }
        __syncthreads();
        const int total = wtot[0] + wtot[1];
        int q = grp;
        for (; q + 48 < total; q += 64) {
            int k0 = lst[q], k1 = lst[q + 16], k2 = lst[q + 32], k3 = lst[q + 48];
            uint4 u0 = xb4[(unsigned)((k0 << 4) | l16)];
            uint4 u1 = xb4[(unsigned)((k1 << 4) | l16)];
            uint4 u2 = xb4[(unsigned)((k2 << 4) | l16)];
            uint4 u3 = xb4[(unsigned)((k3 << 4) | l16)];
            ACCM(a, u0);
            ACCM(a, u1);
            ACCM(a, u2);
            ACCM(a, u3);
        }
        for (; q + 16 < total; q += 32) {
            int k0 = lst[q], k1 = lst[q + 16];
            uint4 u0 = xb4[(unsigned)((k0 << 4) | l16)];
            uint4 u1 = xb4[(unsigned)((k1 << 4) | l16)];
            ACCM(a, u0);
            ACCM(a, u1);
        }
        if (q < total) {
            int k0 = lst[q];
            uint4 u0 = xb4[(unsigned)((k0 << 4) | l16)];
            ACCM(a, u0);
        }
    }

    // ---- cross-group reduction: shuffle within wave, then 4-wave LDS combine ----
    RED2(a0); RED2(a1); RED2(a2); RED2(a3); RED2(a4); RED2(a5); RED2(a6); RED2(a7);
    RED2(b0); RED2(b1); RED2(b2); RED2(b3); RED2(b4); RED2(b5); RED2(b6); RED2(b7);
    __syncthreads();
    if (lane < 16) {
        red[wv][l16 * 8 + 0] = a0; red[wv][l16 * 8 + 1] = a1;
        red[wv][l16 * 8 + 2] = a2; red[wv][l16 * 8 + 3] = a3;
        red[wv][l16 * 8 + 4] = a4; red[wv][l16 * 8 + 5] = a5;
        red[wv][l16 * 8 + 6] = a6; red[wv][l16 * 8 + 7] = a7;
        red[wv][128 + l16 * 8 + 0] = b0; red[wv][128 + l16 * 8 + 1] = b1;
        red[wv][128 + l16 * 8 + 2] = b2; red[wv][128 + l16 * 8 + 3] = b3;
        red[wv][128 + l16 * 8 + 4] = b4; red[wv][128 + l16 * 8 + 5] = b5;
        red[wv][128 + l16 * 8 + 6] = b6; red[wv][128 + l16 * 8 + 7] = b7;
    }
    __syncthreads();
    float s = red[0][tid] + red[1][tid] + red[2][tid] + red[3][tid];
    if (tid < 128) agg2[(size_t)i * C + tid] = s;
    else           agg1[(size_t)i * C + (tid - 128)] = s;
}

// ---- single-pass epilogue: 16 rows/block (750 blocks), f16 k-pair dot2 ----
// Thread: 2 cols x 4 rows. Weights packed half2 over k; agg staged as half2 in LDS.
__global__ __launch_bounds__(256) void epilogue(const float* __restrict__ agg1,
                                                const float* __restrict__ agg2,
                                                const unsigned* __restrict__ Wp1,
                                                const unsigned* __restrict__ Wp2,
                                                const unsigned* __restrict__ Wpf1,
                                                const unsigned* __restrict__ Wpf2,
                                                const float* __restrict__ b1,
                                                const float* __restrict__ b2,
                                                const float* __restrict__ bfused,
                                                float* __restrict__ out) {
    __shared__ unsigned shA[16][64];  // 4 KB: agg1 as half2 k-pairs
    __shared__ unsigned shB[16][64];  // 4 KB
    const int r0 = blockIdx.x * 16;
    const int tid = threadIdx.x;
    const int c0 = (tid & 63) * 2;   // columns c0, c0+1
    const int rg = (tid >> 6) * 4;   // 4 rows per thread

    for (int idx = tid; idx < 512; idx += 256) {
        int r = idx >> 5, q = idx & 31;  // q = group of 4 floats (2 k-pairs)
        float4 fa = *(const float4*)&agg1[(size_t)(r0 + r) * C + q * 4];
        float4 fb = *(const float4*)&agg2[(size_t)(r0 + r) * C + q * 4];
        uint2 ua = {packh2(fa.x, fa.y), packh2(fa.z, fa.w)};
        uint2 ub = {packh2(fb.x, fb.y), packh2(fb.z, fb.w)};
        *(uint2*)&shA[r][q * 2] = ua;
        *(uint2*)&shB[r][q * 2] = ub;
    }
    __syncthreads();

    float z1v[4][2] = {}, z2v[4][2] = {}, gv[4][2] = {};
    for (int t = 0; t < 32; ++t) {   // 2 k-pairs (4 k) per iteration
        const int k2 = t * 2;
        uint2 w1a = *(const uint2*)&Wp1[(size_t)k2 * C + c0];
        uint2 w1b = *(const uint2*)&Wp1[(size_t)(k2 + 1) * C + c0];
        uint2 w2a = *(const uint2*)&Wp2[(size_t)k2 * C + c0];
        uint2 w2b = *(const uint2*)&Wp2[(size_t)(k2 + 1) * C + c0];
        uint2 f1a = *(const uint2*)&Wpf1[(size_t)k2 * C + c0];
        uint2 f1b = *(const uint2*)&Wpf1[(size_t)(k2 + 1) * C + c0];
        uint2 f2a = *(const uint2*)&Wpf2[(size_t)k2 * C + c0];
        uint2 f2b = *(const uint2*)&Wpf2[(size_t)(k2 + 1) * C + c0];
#pragma unroll
        for (int r = 0; r < 4; ++r) {
            uint2 aA = *(const uint2*)&shA[rg + r][k2];
            uint2 aB = *(const uint2*)&shB[rg + r][k2];
            dot2acc(z1v[r][0], aA.x, w1a.x); dot2acc(z1v[r][0], aA.y, w1b.x);
            dot2acc(z1v[r][1], aA.x, w1a.y); dot2acc(z1v[r][1], aA.y, w1b.y);
            dot2acc(z2v[r][0], aB.x, w2a.x); dot2acc(z2v[r][0], aB.y, w2b.x);
            dot2acc(z2v[r][1], aB.x, w2a.y); dot2acc(z2v[r][1], aB.y, w2b.y);
            dot2acc(gv[r][0], aA.x, f1a.x);  dot2acc(gv[r][0], aA.y, f1b.x);
            dot2acc(gv[r][1], aA.x, f1a.y);  dot2acc(gv[r][1], aA.y, f1b.y);
            dot2acc(gv[r][0], aB.x, f2a.x);  dot2acc(gv[r][0], aB.y, f2b.x);
            dot2acc(gv[r][1], aB.x, f2a.y);  dot2acc(gv[r][1], aB.y, f2b.y);
        }
    }
    const float2 b1v = *(const float2*)&b1[c0];
    const float2 b2v = *(const float2*)&b2[c0];
    const float2 bfv = *(const float2*)&bfused[c0];
#pragma unroll
    for (int r = 0; r < 4; ++r) {
        float g0 = 1.f / (1.f + expf(-(gv[r][0] + bfv.x)));
        float g1 = 1.f / (1.f + expf(-(gv[r][1] + bfv.y)));
        float2 res;
        res.x = g0 * (z1v[r][0] + b1v.x) + (1.f - g0) * (z2v[r][0] + b2v.x);
        res.y = g1 * (z1v[r][1] + b1v.y) + (1.f - g1) * (z2v[r][1] + b2v.y);
        *(float2*)&out[(size_t)(r0 + rg + r) * C + c0] = res;
    }
}

extern "C" void kernel_launch(void* const* d_in, const int* in_sizes, int n_in,
                              void* d_out, int out_size, void* d_ws, size_t ws_size,
                              hipStream_t stream) {
    const float* x  = (const float*)d_in[0];
    const int*   ei = (const int*)d_in[1];
    const float* W1 = (const float*)d_in[2];
    const float* b1 = (const float*)d_in[3];
    const float* W2 = (const float*)d_in[4];
    const float* b2 = (const float*)d_in[5];
    const float* Wg = (const float*)d_in[6];
    const float* bg = (const float*)d_in[7];
    float* out = (float*)d_out;

    char* ws = (char*)d_ws;
    size_t o = 0;
    auto alloc = [&](size_t bytes) { char* p = ws + o; o = (o + bytes + 255) & ~(size_t)255; return p; };
    int* col      = (int*)alloc((size_t)NEDGE * 4);
    int* deg      = (int*)alloc((size_t)N_NODES * 2 * 4);   // deg + cur contiguous
    int* cur      = deg + N_NODES;
    int* off      = (int*)alloc((size_t)(N_NODES + 1) * 4);
    unsigned* xb  = (unsigned*)alloc((size_t)N_NODES * C * 2);  // f16 x
    float* agg1   = (float*)alloc((size_t)N_NODES * C * 4);
    float* agg2   = (float*)alloc((size_t)N_NODES * C * 4);
    unsigned* Wp1  = (unsigned*)alloc((size_t)(C / 2) * C * 4);  // 32 KB each
    unsigned* Wp2  = (unsigned*)alloc((size_t)(C / 2) * C * 4);
    unsigned* Wpf1 = (unsigned*)alloc((size_t)(C / 2) * C * 4);
    unsigned* Wpf2 = (unsigned*)alloc((size_t)(C / 2) * C * 4);
    float* bfused  = (float*)alloc((size_t)C * 4);
    // total ~16.5 MB (proven safe)

    hipMemsetAsync(deg, 0, (size_t)N_NODES * 2 * 4, stream);

    prep_fuse<<<3128, 256, 0, stream>>>(x, xb, ei, deg, W1, W2, Wg, b1, b2, bg,
                                        Wp1, Wp2, Wpf1, Wpf2, bfused);
    scan_offsets<<<1, 1024, 0, stream>>>(deg, off);
    fill_csr<<<(NEDGE + 255) / 256, 256, 0, stream>>>(ei, off, cur, col);
    twohop_fused<<<N_NODES, 256, 0, stream>>>(off, col, xb, agg1, agg2);
    epilogue<<<N_NODES / 16, 256, 0, stream>>>(agg1, agg2, Wp1, Wp2, Wpf1, Wpf2,
                                               b1, b2, bfused, out);
}

// Round 15
// 141.510 us; speedup vs baseline: 1.4569x; 1.0569x over previous
//
#include <hip/hip_runtime.h>
#include <hip/hip_fp16.h>
#include <math.h>

#define N_NODES 12000
#define C 128
#define NEDGE 192000
#define BW 384  // u32 words per LDS dedup bitset (12288 bits >= 12000)
#define MSK 0x7FFFFFFF

// acc_lo += s*(float)f16_lo(u); acc_hi += s*(float)f16_hi(u)  -- one VOP3P each
__device__ __forceinline__ void fmix2(float& lo, float& hi, unsigned u, float s) {
    asm("v_fma_mix_f32 %0, %2, %3, %0 op_sel:[0,0,0] op_sel_hi:[1,0,0]\n\t"
        "v_fma_mix_f32 %1, %2, %3, %1 op_sel:[1,0,0] op_sel_hi:[1,0,0]"
        : "+v"(lo), "+v"(hi)
        : "v"(u), "v"(s));
}

// acc += a.lo*b.lo + a.hi*b.hi  (f16 pairs, f32 accumulate) -- one VOP3P
__device__ __forceinline__ void dot2acc(float& acc, unsigned a, unsigned b) {
    asm("v_dot2_f32_f16 %0, %1, %2, %0" : "+v"(acc) : "v"(a), "v"(b));
}

__device__ __forceinline__ unsigned packh2(float lo, float hi) {
    __half2 h = __floats2half2_rn(lo, hi);
    return *reinterpret_cast<unsigned*>(&h);
}

#define ACCM(p, u)                                            \
    fmix2(p##0, p##1, u.x, one); fmix2(p##2, p##3, u.y, one); \
    fmix2(p##4, p##5, u.z, one); fmix2(p##6, p##7, u.w, one)

#define RED2(x) x += __shfl_xor(x, 16); x += __shfl_xor(x, 32)

// ---- merged: x->f16 + degree hist (blocks 0..2999) | weight fuse+pack (blocks 3000..3127) ----
__global__ __launch_bounds__(256) void prep_fuse(const float* __restrict__ x,
                                                 unsigned* __restrict__ xbu,
                                                 const int* __restrict__ ei,
                                                 int* __restrict__ deg,
                                                 const float* __restrict__ W1,
                                                 const float* __restrict__ W2,
                                                 const float* __restrict__ Wg,
                                                 const float* __restrict__ b1,
                                                 const float* __restrict__ b2,
                                                 const float* __restrict__ bg,
                                                 unsigned* __restrict__ Wp1,
                                                 unsigned* __restrict__ Wp2,
                                                 unsigned* __restrict__ Wpf1,
                                                 unsigned* __restrict__ Wpf2,
                                                 float* __restrict__ bfused) {
    const int tid = threadIdx.x;
    if (blockIdx.x < 3000) {
        int g = blockIdx.x * 256 + tid;
        if (g < N_NODES * C / 2) {
            unsigned pa = __half_as_ushort(__float2half(x[2 * g]));
            unsigned pb = __half_as_ushort(__float2half(x[2 * g + 1]));
            xbu[g] = pa | (pb << 16);
        }
        if (g < NEDGE) atomicAdd(&deg[ei[g]], 1);
        return;
    }
    __shared__ __align__(16) float wg1[C];
    __shared__ __align__(16) float wg2[C];
    __shared__ float sb[C];
    __shared__ float l1[C], l2[C], lf1[C], lf2[C];
    const int c = blockIdx.x - 3000;
    const int j = tid;
    if (j < 128) {
        float g1 = Wg[(size_t)j * C + c];
        float g2 = Wg[(size_t)(C + j) * C + c];
        wg1[j] = g1;
        wg2[j] = g2;
        sb[j] = b1[j] * g1 + b2[j] * g2;
    }
    __syncthreads();
    if (j < 128) {
        float s1 = 0.f, s2 = 0.f;
        for (int k = 0; k < C; k += 4) {
            float4 a = *(const float4*)&W1[(size_t)j * C + k];
            float4 b = *(const float4*)&W2[(size_t)j * C + k];
            float4 u = *(const float4*)&wg1[k];
            float4 v = *(const float4*)&wg2[k];
            s1 += a.x * u.x + a.y * u.y + a.z * u.z + a.w * u.w;
            s2 += b.x * v.x + b.y * v.y + b.z * v.z + b.w * v.w;
        }
        l1[j] = W1[(size_t)j * C + c];
        l2[j] = W2[(size_t)j * C + c];
        lf1[j] = s1;
        lf2[j] = s2;
    }
    __syncthreads();
    if (j < 64) {
        Wp1[(size_t)j * C + c]  = packh2(l1[2 * j], l1[2 * j + 1]);
        Wp2[(size_t)j * C + c]  = packh2(l2[2 * j], l2[2 * j + 1]);
        Wpf1[(size_t)j * C + c] = packh2(lf1[2 * j], lf1[2 * j + 1]);
        Wpf2[(size_t)j * C + c] = packh2(lf2[2 * j], lf2[2 * j + 1]);
    }
    if (j == 0) {
        float s = bg[c];
        for (int k = 0; k < C; ++k) s += sb[k];
        bfused[c] = s;
    }
}

// ---- exclusive scan of degrees -> CSR offsets (single 1024-thread block) ----
__global__ __launch_bounds__(1024) void scan_offsets(const int* __restrict__ deg,
                                                     int* __restrict__ off) {
    __shared__ int wsum[16];
    const int t = threadIdx.x;
    const int lane = t & 63, wv = t >> 6;
    const int PER = 12;
    const int lo = t * PER;
    int local[PER];
    int sum = 0;
#pragma unroll
    for (int k = 0; k < PER; ++k) {
        int i = lo + k;
        int d = (i < N_NODES) ? deg[i] : 0;
        local[k] = sum;
        sum += d;
    }
    int p = sum;
    for (int d = 1; d < 64; d <<= 1) {
        int u = __shfl_up(p, d);
        if (lane >= d) p += u;
    }
    if (lane == 63) wsum[wv] = p;
    __syncthreads();
    int wbase = 0;
    for (int k = 0; k < wv; ++k) wbase += wsum[k];
    const int tbase = wbase + p - sum;
#pragma unroll
    for (int k = 0; k < PER; ++k) {
        int i = lo + k;
        if (i < N_NODES) off[i] = tbase + local[k];
    }
    if (t == 0) off[N_NODES] = NEDGE;
}

// ---- fill CSR columns (order within row irrelevant; duplicates kept) ----
__global__ void fill_csr(const int* __restrict__ ei, const int* __restrict__ off,
                         int* __restrict__ cur, int* __restrict__ col) {
    int e = blockIdx.x * blockDim.x + threadIdx.x;
    if (e >= NEDGE) return;
    int s = ei[e];
    int t = ei[NEDGE + e];
    int pos = atomicAdd(&cur[s], 1);
    col[off[s] + pos] = t;
}

// ---- mark duplicate edges (sign bit) + h = Adj_bin @ x (fp32). wave per node. ----
__global__ __launch_bounds__(256) void markdup_h(const int* __restrict__ off,
                                                 int* __restrict__ col,
                                                 const unsigned* __restrict__ xb,
                                                 float* __restrict__ hf) {
    __shared__ int rows[4][256];
    const int tid = threadIdx.x;
    const int lane = tid & 63, wv = tid >> 6;
    const int i = blockIdx.x * 4 + wv;
    const int rb = off[i], re = off[i + 1];
    const int d = re - rb;
    const int dc = d < 256 ? d : 256;
    const uint4* xb4 = (const uint4*)xb;
    const float one = 1.0f;

    for (int e = lane; e < dc; e += 64) rows[wv][e] = col[rb + e];
    // mark duplicates: entry e dup iff exists e2 < e with same value (mask-compare is race-safe)
    for (int e = lane; e < dc; e += 64) {
        int vm = rows[wv][e] & MSK;
        bool dup = false;
        for (int e2 = 0; e2 < e; ++e2)
            if ((rows[wv][e2] & MSK) == vm) { dup = true; break; }
        if (dup) {
            rows[wv][e] = vm | 0x80000000;
            col[rb + e] = vm | 0x80000000;   // visible to next dispatch
        }
    }
    __syncthreads();

    // h gather over unmarked entries: 4 groups of 16 lanes per wave
    const int g = lane >> 4, l16 = lane & 15;
    float a0 = 0, a1 = 0, a2 = 0, a3 = 0, a4 = 0, a5 = 0, a6 = 0, a7 = 0;
    for (int e = g; e < d; e += 4) {
        int c0 = (e < 256) ? rows[wv][e] : col[rb + e];
        if (c0 >= 0) {
            uint4 u = xb4[(unsigned)((c0 << 4) | l16)];
            ACCM(a, u);
        }
    }
    RED2(a0); RED2(a1); RED2(a2); RED2(a3); RED2(a4); RED2(a5); RED2(a6); RED2(a7);
    if (lane < 16) {
        float4 h0 = {a0, a1, a2, a3}, h1 = {a4, a5, a6, a7};
        *(float4*)&hf[(size_t)i * C + l16 * 8] = h0;
        *(float4*)&hf[(size_t)i * C + l16 * 8 + 4] = h1;
    }
}

// ---- fused: agg1 (multiplicity) + t = Adj@h + test-and-set corrections -> agg2 ----
__global__ __launch_bounds__(256) void twohop_fused(const int* __restrict__ off,
                                                    const int* __restrict__ col,
                                                    const unsigned* __restrict__ xb,
                                                    const float* __restrict__ hf,
                                                    float* __restrict__ agg1,
                                                    float* __restrict__ agg2) {
    __shared__ unsigned acc[BW];          // 1.5 KB dedup bitset
    __shared__ int sjb[64];
    __shared__ int spos[64];
    __shared__ int stot;
    __shared__ int ncorr;
    __shared__ unsigned short corr[512];  // 1 KB; avg ~3 used
    __shared__ float red[4][256];         // 4 KB
    const int i = blockIdx.x;
    const int tid = threadIdx.x;
    const int lane = tid & 63;
    const int wv = tid >> 6;
    const int grp = tid >> 4, l16 = tid & 15;
    const int rowbeg = off[i], rowend = off[i + 1];
    const uint4* xb4 = (const uint4*)xb;
    const float one = 1.0f, neg1 = -1.0f;

    for (int w = tid; w < BW; w += 256) acc[w] = 0u;
    if (tid == 0) ncorr = 0;
    __syncthreads();

    // ---- union with test-and-set corrections, flattened per 64-neighbor chunk ----
    for (int base = rowbeg; base < rowend; base += 64) {
        int d = rowend - base;
        if (d > 64) d = 64;
        if (tid < 64) {
            int len = 0;
            if (tid < d) {
                int j = col[base + tid];
                if (j >= 0) {               // skip duplicate edges (binary adjacency)
                    int jb = off[j];
                    len = off[j + 1] - jb;
                    sjb[tid] = jb;
                }
            }
            int p = len;
            for (int dd = 1; dd < 64; dd <<= 1) {
                int u = __shfl_up(p, dd);
                if (lane >= dd) p += u;
            }
            spos[tid] = p - len;
            if (tid == 63) stot = p;
        }
        __syncthreads();
        const int total = stot;
        for (int q = tid; q < total; q += 256) {
            int lo = 0, hi = d - 1;
            while (lo < hi) {
                int mid = (lo + hi + 1) >> 1;
                if (spos[mid] <= q) lo = mid; else hi = mid - 1;
            }
            int t = col[sjb[lo] + (q - spos[lo])];
            if (t >= 0) {                   // skip marked entries in j's row
                unsigned bit = 1u << (t & 31);
                unsigned old = atomicOr(&acc[t >> 5], bit);
                if (old & bit) {            // duplicate 2-path: correction
                    int pos = atomicAdd(&ncorr, 1);
                    if (pos < 512) corr[pos] = (unsigned short)t;
                }
            }
        }
        __syncthreads();
    }
    // diagonal: if i reachable in 2 hops, subtract its remaining copy
    if (tid == 0) {
        if (acc[i >> 5] & (1u << (i & 31))) {
            int pos = atomicAdd(&ncorr, 1);
            if (pos < 512) corr[pos] = (unsigned short)i;
        }
    }

    // ---- row gather: agg1 (xb, all entries) + t (hf, unmarked entries) ----
    float b0 = 0, b1 = 0, b2 = 0, b3 = 0, b4 = 0, b5 = 0, b6 = 0, b7 = 0;
    float a0 = 0, a1 = 0, a2 = 0, a3 = 0, a4 = 0, a5 = 0, a6 = 0, a7 = 0;
    for (int idx = rowbeg + grp; idx < rowend; idx += 16) {
        int c0 = col[idx];
        int k = c0 & MSK;
        uint4 u = xb4[(unsigned)((k << 4) | l16)];
        ACCM(b, u);
        if (c0 >= 0) {
            float4 h0 = *(const float4*)&hf[(size_t)k * C + l16 * 8];
            float4 h1 = *(const float4*)&hf[(size_t)k * C + l16 * 8 + 4];
            a0 += h0.x; a1 += h0.y; a2 += h0.z; a3 += h0.w;
            a4 += h1.x; a5 += h1.y; a6 += h1.z; a7 += h1.w;
        }
    }
    __syncthreads();  // corr/ncorr complete

    // ---- corrections: subtract x_t for each extra 2-path occurrence ----
    {
        int nc = ncorr < 512 ? ncorr : 512;
        for (int q = grp; q < nc; q += 16) {
            int t = corr[q];
            uint4 u = xb4[(unsigned)((t << 4) | l16)];
            fmix2(a0, a1, u.x, neg1);
            fmix2(a2, a3, u.y, neg1);
            fmix2(a4, a5, u.z, neg1);
            fmix2(a6, a7, u.w, neg1);
        }
    }

    // ---- cross-group reduction: shuffle within wave, then 4-wave LDS combine ----
    RED2(a0); RED2(a1); RED2(a2); RED2(a3); RED2(a4); RED2(a5); RED2(a6); RED2(a7);
    RED2(b0); RED2(b1); RED2(b2); RED2(b3); RED2(b4); RED2(b5); RED2(b6); RED2(b7);
    __syncthreads();
    if (lane < 16) {
        red[wv][l16 * 8 + 0] = a0; red[wv][l16 * 8 + 1] = a1;
        red[wv][l16 * 8 + 2] = a2; red[wv][l16 * 8 + 3] = a3;
        red[wv][l16 * 8 + 4] = a4; red[wv][l16 * 8 + 5] = a5;
        red[wv][l16 * 8 + 6] = a6; red[wv][l16 * 8 + 7] = a7;
        red[wv][128 + l16 * 8 + 0] = b0; red[wv][128 + l16 * 8 + 1] = b1;
        red[wv][128 + l16 * 8 + 2] = b2; red[wv][128 + l16 * 8 + 3] = b3;
        red[wv][128 + l16 * 8 + 4] = b4; red[wv][128 + l16 * 8 + 5] = b5;
        red[wv][128 + l16 * 8 + 6] = b6; red[wv][128 + l16 * 8 + 7] = b7;
    }
    __syncthreads();
    float s = red[0][tid] + red[1][tid] + red[2][tid] + red[3][tid];
    if (tid < 128) agg2[(size_t)i * C + tid] = s;
    else           agg1[(size_t)i * C + (tid - 128)] = s;
}

// ---- single-pass epilogue: 16 rows/block (750 blocks), f16 k-pair dot2 ----
__global__ __launch_bounds__(256) void epilogue(const float* __restrict__ agg1,
                                                const float* __restrict__ agg2,
                                                const unsigned* __restrict__ Wp1,
                                                const unsigned* __restrict__ Wp2,
                                                const unsigned* __restrict__ Wpf1,
                                                const unsigned* __restrict__ Wpf2,
                                                const float* __restrict__ b1,
                                                const float* __restrict__ b2,
                                                const float* __restrict__ bfused,
                                                float* __restrict__ out) {
    __shared__ unsigned shA[16][64];
    __shared__ unsigned shB[16][64];
    const int r0 = blockIdx.x * 16;
    const int tid = threadIdx.x;
    const int c0 = (tid & 63) * 2;
    const int rg = (tid >> 6) * 4;

    for (int idx = tid; idx < 512; idx += 256) {
        int r = idx >> 5, q = idx & 31;
        float4 fa = *(const float4*)&agg1[(size_t)(r0 + r) * C + q * 4];
        float4 fb = *(const float4*)&agg2[(size_t)(r0 + r) * C + q * 4];
        uint2 ua = {packh2(fa.x, fa.y), packh2(fa.z, fa.w)};
        uint2 ub = {packh2(fb.x, fb.y), packh2(fb.z, fb.w)};
        *(uint2*)&shA[r][q * 2] = ua;
        *(uint2*)&shB[r][q * 2] = ub;
    }
    __syncthreads();

    float z1v[4][2] = {}, z2v[4][2] = {}, gv[4][2] = {};
    for (int t = 0; t < 32; ++t) {
        const int k2 = t * 2;
        uint2 w1a = *(const uint2*)&Wp1[(size_t)k2 * C + c0];
        uint2 w1b = *(const uint2*)&Wp1[(size_t)(k2 + 1) * C + c0];
        uint2 w2a = *(const uint2*)&Wp2[(size_t)k2 * C + c0];
        uint2 w2b = *(const uint2*)&Wp2[(size_t)(k2 + 1) * C + c0];
        uint2 f1a = *(const uint2*)&Wpf1[(size_t)k2 * C + c0];
        uint2 f1b = *(const uint2*)&Wpf1[(size_t)(k2 + 1) * C + c0];
        uint2 f2a = *(const uint2*)&Wpf2[(size_t)k2 * C + c0];
        uint2 f2b = *(const uint2*)&Wpf2[(size_t)(k2 + 1) * C + c0];
#pragma unroll
        for (int r = 0; r < 4; ++r) {
            uint2 aA = *(const uint2*)&shA[rg + r][k2];
            uint2 aB = *(const uint2*)&shB[rg + r][k2];
            dot2acc(z1v[r][0], aA.x, w1a.x); dot2acc(z1v[r][0], aA.y, w1b.x);
            dot2acc(z1v[r][1], aA.x, w1a.y); dot2acc(z1v[r][1], aA.y, w1b.y);
            dot2acc(z2v[r][0], aB.x, w2a.x); dot2acc(z2v[r][0], aB.y, w2b.x);
            dot2acc(z2v[r][1], aB.x, w2a.y); dot2acc(z2v[r][1], aB.y, w2b.y);
            dot2acc(gv[r][0], aA.x, f1a.x);  dot2acc(gv[r][0], aA.y, f1b.x);
            dot2acc(gv[r][1], aA.x, f1a.y);  dot2acc(gv[r][1], aA.y, f1b.y);
            dot2acc(gv[r][0], aB.x, f2a.x);  dot2acc(gv[r][0], aB.y, f2b.x);
            dot2acc(gv[r][1], aB.x, f2a.y);  dot2acc(gv[r][1], aB.y, f2b.y);
        }
    }
    const float2 b1v = *(const float2*)&b1[c0];
    const float2 b2v = *(const float2*)&b2[c0];
    const float2 bfv = *(const float2*)&bfused[c0];
#pragma unroll
    for (int r = 0; r < 4; ++r) {
        float g0 = 1.f / (1.f + expf(-(gv[r][0] + bfv.x)));
        float g1 = 1.f / (1.f + expf(-(gv[r][1] + bfv.y)));
        float2 res;
        res.x = g0 * (z1v[r][0] + b1v.x) + (1.f - g0) * (z2v[r][0] + b2v.x);
        res.y = g1 * (z1v[r][1] + b1v.y) + (1.f - g1) * (z2v[r][1] + b2v.y);
        *(float2*)&out[(size_t)(r0 + rg + r) * C + c0] = res;
    }
}

extern "C" void kernel_launch(void* const* d_in, const int* in_sizes, int n_in,
                              void* d_out, int out_size, void* d_ws, size_t ws_size,
                              hipStream_t stream) {
    const float* x  = (const float*)d_in[0];
    const int*   ei = (const int*)d_in[1];
    const float* W1 = (const float*)d_in[2];
    const float* b1 = (const float*)d_in[3];
    const float* W2 = (const float*)d_in[4];
    const float* b2 = (const float*)d_in[5];
    const float* Wg = (const float*)d_in[6];
    const float* bg = (const float*)d_in[7];
    float* out = (float*)d_out;

    char* ws = (char*)d_ws;
    size_t o = 0;
    auto alloc = [&](size_t bytes) { char* p = ws + o; o = (o + bytes + 255) & ~(size_t)255; return p; };
    int* col      = (int*)alloc((size_t)NEDGE * 4);
    int* deg      = (int*)alloc((size_t)N_NODES * 2 * 4);
    int* cur      = deg + N_NODES;
    int* off      = (int*)alloc((size_t)(N_NODES + 1) * 4);
    unsigned* xb  = (unsigned*)alloc((size_t)N_NODES * C * 2);  // f16 x
    float* agg1   = (float*)alloc((size_t)N_NODES * C * 4);
    float* agg2   = (float*)alloc((size_t)N_NODES * C * 4);
    float* hf     = (float*)alloc((size_t)N_NODES * C * 4);     // fp32 h = Adj@x
    unsigned* Wp1  = (unsigned*)alloc((size_t)(C / 2) * C * 4);
    unsigned* Wp2  = (unsigned*)alloc((size_t)(C / 2) * C * 4);
    unsigned* Wpf1 = (unsigned*)alloc((size_t)(C / 2) * C * 4);
    unsigned* Wpf2 = (unsigned*)alloc((size_t)(C / 2) * C * 4);
    float* bfused  = (float*)alloc((size_t)C * 4);
    // total ~22.5 MB (< 30.7 MB proven safe in round 1)

    hipMemsetAsync(deg, 0, (size_t)N_NODES * 2 * 4, stream);

    prep_fuse<<<3128, 256, 0, stream>>>(x, xb, ei, deg, W1, W2, Wg, b1, b2, bg,
                                        Wp1, Wp2, Wpf1, Wpf2, bfused);
    scan_offsets<<<1, 1024, 0, stream>>>(deg, off);
    fill_csr<<<(NEDGE + 255) / 256, 256, 0, stream>>>(ei, off, cur, col);
    markdup_h<<<N_NODES / 4, 256, 0, stream>>>(off, col, xb, hf);
    twohop_fused<<<N_NODES, 256, 0, stream>>>(off, col, xb, hf, agg1, agg2);
    epilogue<<<N_NODES / 16, 256, 0, stream>>>(agg1, agg2, Wp1, Wp2, Wpf1, Wpf2,
                                               b1, b2, bfused, out);
}

// Round 16
// 130.632 us; speedup vs baseline: 1.5782x; 1.0833x over previous
//
#include <hip/hip_runtime.h>
#include <hip/hip_fp16.h>
#include <math.h>

#define N_NODES 12000
#define C 128
#define NEDGE 192000
#define BW 384  // u32 words per LDS dedup bitset (12288 bits >= 12000)
#define MSK 0x7FFFFFFF

// acc_lo += s*(float)f16_lo(u); acc_hi += s*(float)f16_hi(u)  -- one VOP3P each
__device__ __forceinline__ void fmix2(float& lo, float& hi, unsigned u, float s) {
    asm("v_fma_mix_f32 %0, %2, %3, %0 op_sel:[0,0,0] op_sel_hi:[1,0,0]\n\t"
        "v_fma_mix_f32 %1, %2, %3, %1 op_sel:[1,0,0] op_sel_hi:[1,0,0]"
        : "+v"(lo), "+v"(hi)
        : "v"(u), "v"(s));
}

// acc += a.lo*b.lo + a.hi*b.hi  (f16 pairs, f32 accumulate) -- one VOP3P
__device__ __forceinline__ void dot2acc(float& acc, unsigned a, unsigned b) {
    asm("v_dot2_f32_f16 %0, %1, %2, %0" : "+v"(acc) : "v"(a), "v"(b));
}

__device__ __forceinline__ unsigned packh2(float lo, float hi) {
    __half2 h = __floats2half2_rn(lo, hi);
    return *reinterpret_cast<unsigned*>(&h);
}

#define ACCM(p, u)                                            \
    fmix2(p##0, p##1, u.x, one); fmix2(p##2, p##3, u.y, one); \
    fmix2(p##4, p##5, u.z, one); fmix2(p##6, p##7, u.w, one)

#define RED2(x) x += __shfl_xor(x, 16); x += __shfl_xor(x, 32)

// ---- merged: x->f16 + degree hist (blocks 0..2999) | weight fuse+pack (blocks 3000..3127) ----
__global__ __launch_bounds__(256) void prep_fuse(const float* __restrict__ x,
                                                 unsigned* __restrict__ xbu,
                                                 const int* __restrict__ ei,
                                                 int* __restrict__ deg,
                                                 const float* __restrict__ W1,
                                                 const float* __restrict__ W2,
                                                 const float* __restrict__ Wg,
                                                 const float* __restrict__ b1,
                                                 const float* __restrict__ b2,
                                                 const float* __restrict__ bg,
                                                 unsigned* __restrict__ Wp1,
                                                 unsigned* __restrict__ Wp2,
                                                 unsigned* __restrict__ Wpf1,
                                                 unsigned* __restrict__ Wpf2,
                                                 float* __restrict__ bfused) {
    const int tid = threadIdx.x;
    if (blockIdx.x < 3000) {
        int g = blockIdx.x * 256 + tid;
        if (g < N_NODES * C / 2) {
            unsigned pa = __half_as_ushort(__float2half(x[2 * g]));
            unsigned pb = __half_as_ushort(__float2half(x[2 * g + 1]));
            xbu[g] = pa | (pb << 16);
        }
        if (g < NEDGE) atomicAdd(&deg[ei[g]], 1);
        return;
    }
    __shared__ __align__(16) float wg1[C];
    __shared__ __align__(16) float wg2[C];
    __shared__ float sb[C];
    __shared__ float l1[C], l2[C], lf1[C], lf2[C];
    const int c = blockIdx.x - 3000;
    const int j = tid;
    if (j < 128) {
        float g1 = Wg[(size_t)j * C + c];
        float g2 = Wg[(size_t)(C + j) * C + c];
        wg1[j] = g1;
        wg2[j] = g2;
        sb[j] = b1[j] * g1 + b2[j] * g2;
    }
    __syncthreads();
    if (j < 128) {
        float s1 = 0.f, s2 = 0.f;
        for (int k = 0; k < C; k += 4) {
            float4 a = *(const float4*)&W1[(size_t)j * C + k];
            float4 b = *(const float4*)&W2[(size_t)j * C + k];
            float4 u = *(const float4*)&wg1[k];
            float4 v = *(const float4*)&wg2[k];
            s1 += a.x * u.x + a.y * u.y + a.z * u.z + a.w * u.w;
            s2 += b.x * v.x + b.y * v.y + b.z * v.z + b.w * v.w;
        }
        l1[j] = W1[(size_t)j * C + c];
        l2[j] = W2[(size_t)j * C + c];
        lf1[j] = s1;
        lf2[j] = s2;
    }
    __syncthreads();
    if (j < 64) {
        Wp1[(size_t)j * C + c]  = packh2(l1[2 * j], l1[2 * j + 1]);
        Wp2[(size_t)j * C + c]  = packh2(l2[2 * j], l2[2 * j + 1]);
        Wpf1[(size_t)j * C + c] = packh2(lf1[2 * j], lf1[2 * j + 1]);
        Wpf2[(size_t)j * C + c] = packh2(lf2[2 * j], lf2[2 * j + 1]);
    }
    if (j == 0) {
        float s = bg[c];
        for (int k = 0; k < C; ++k) s += sb[k];
        bfused[c] = s;
    }
}

// ---- exclusive scan of degrees -> CSR offsets (single 1024-thread block) ----
__global__ __launch_bounds__(1024) void scan_offsets(const int* __restrict__ deg,
                                                     int* __restrict__ off) {
    __shared__ int wsum[16];
    const int t = threadIdx.x;
    const int lane = t & 63, wv = t >> 6;
    const int PER = 12;
    const int lo = t * PER;
    int local[PER];
    int sum = 0;
#pragma unroll
    for (int k = 0; k < PER; ++k) {
        int i = lo + k;
        int d = (i < N_NODES) ? deg[i] : 0;
        local[k] = sum;
        sum += d;
    }
    int p = sum;
    for (int d = 1; d < 64; d <<= 1) {
        int u = __shfl_up(p, d);
        if (lane >= d) p += u;
    }
    if (lane == 63) wsum[wv] = p;
    __syncthreads();
    int wbase = 0;
    for (int k = 0; k < wv; ++k) wbase += wsum[k];
    const int tbase = wbase + p - sum;
#pragma unroll
    for (int k = 0; k < PER; ++k) {
        int i = lo + k;
        if (i < N_NODES) off[i] = tbase + local[k];
    }
    if (t == 0) off[N_NODES] = NEDGE;
}

// ---- fill CSR columns (order within row irrelevant; duplicates kept) ----
__global__ void fill_csr(const int* __restrict__ ei, const int* __restrict__ off,
                         int* __restrict__ cur, int* __restrict__ col) {
    int e = blockIdx.x * blockDim.x + threadIdx.x;
    if (e >= NEDGE) return;
    int s = ei[e];
    int t = ei[NEDGE + e];
    int pos = atomicAdd(&cur[s], 1);
    col[off[s] + pos] = t;
}

// ---- mark dup edges (sign bit) + h(dedup, f16 out) + agg1(multiplicity, fp32 out) ----
// One wave per node; both aggregates share the same xb row loads.
__global__ __launch_bounds__(256) void markdup_h(const int* __restrict__ off,
                                                 int* __restrict__ col,
                                                 const unsigned* __restrict__ xb,
                                                 unsigned* __restrict__ hb,
                                                 float* __restrict__ agg1) {
    __shared__ int rows[4][256];
    const int tid = threadIdx.x;
    const int lane = tid & 63, wv = tid >> 6;
    const int i = blockIdx.x * 4 + wv;
    const int rb = off[i], re = off[i + 1];
    const int d = re - rb;
    const int dc = d < 256 ? d : 256;
    const uint4* xb4 = (const uint4*)xb;
    const float one = 1.0f;

    for (int e = lane; e < dc; e += 64) rows[wv][e] = col[rb + e];
    // mark duplicates: entry e dup iff exists e2 < e with same value (mask-compare is race-safe)
    for (int e = lane; e < dc; e += 64) {
        int vm = rows[wv][e] & MSK;
        bool dup = false;
        for (int e2 = 0; e2 < e; ++e2)
            if ((rows[wv][e2] & MSK) == vm) { dup = true; break; }
        if (dup) {
            rows[wv][e] = vm | 0x80000000;
            col[rb + e] = vm | 0x80000000;   // visible to next dispatch
        }
    }
    __syncthreads();

    // gather: b = all entries (agg1), a = unmarked only (h); one load serves both
    const int g = lane >> 4, l16 = lane & 15;
    float a0 = 0, a1 = 0, a2 = 0, a3 = 0, a4 = 0, a5 = 0, a6 = 0, a7 = 0;
    float b0 = 0, b1 = 0, b2 = 0, b3 = 0, b4 = 0, b5 = 0, b6 = 0, b7 = 0;
    for (int e = g; e < d; e += 4) {
        int c0 = (e < 256) ? rows[wv][e] : col[rb + e];
        int k = c0 & MSK;
        uint4 u = xb4[(unsigned)((k << 4) | l16)];
        ACCM(b, u);
        if (c0 >= 0) { ACCM(a, u); }
    }
    RED2(a0); RED2(a1); RED2(a2); RED2(a3); RED2(a4); RED2(a5); RED2(a6); RED2(a7);
    RED2(b0); RED2(b1); RED2(b2); RED2(b3); RED2(b4); RED2(b5); RED2(b6); RED2(b7);
    if (lane < 16) {
        uint4 hp = {packh2(a0, a1), packh2(a2, a3), packh2(a4, a5), packh2(a6, a7)};
        ((uint4*)hb)[(unsigned)((i << 4) | l16)] = hp;
        float4 w0 = {b0, b1, b2, b3}, w1 = {b4, b5, b6, b7};
        *(float4*)&agg1[(size_t)i * C + l16 * 8] = w0;
        *(float4*)&agg1[(size_t)i * C + l16 * 8 + 4] = w1;
    }
}

// ---- fused: union + test-and-set corrections + agg2 = Adj_bin@h - corrections ----
__global__ __launch_bounds__(256) void twohop_fused(const int* __restrict__ off,
                                                    const int* __restrict__ col,
                                                    const unsigned* __restrict__ xb,
                                                    const unsigned* __restrict__ hb,
                                                    float* __restrict__ agg2) {
    __shared__ unsigned acc[BW];          // 1.5 KB dedup bitset
    __shared__ int sjb[64];
    __shared__ int spos[64];
    __shared__ int stot;
    __shared__ int ncorr;
    __shared__ unsigned short corr[512];  // 1 KB; avg ~3 used
    __shared__ float red[4][128];         // 2 KB
    const int i = blockIdx.x;
    const int tid = threadIdx.x;
    const int lane = tid & 63;
    const int wv = tid >> 6;
    const int grp = tid >> 4, l16 = tid & 15;
    const int rowbeg = off[i], rowend = off[i + 1];
    const uint4* xb4 = (const uint4*)xb;
    const uint4* hb4 = (const uint4*)hb;
    const float one = 1.0f, neg1 = -1.0f;

    for (int w = tid; w < BW; w += 256) acc[w] = 0u;
    if (tid == 0) ncorr = 0;
    __syncthreads();

    // ---- union with test-and-set corrections, flattened per 64-neighbor chunk ----
    for (int base = rowbeg; base < rowend; base += 64) {
        int d = rowend - base;
        if (d > 64) d = 64;
        if (tid < 64) {
            int len = 0;
            if (tid < d) {
                int j = col[base + tid];
                if (j >= 0) {               // skip duplicate edges (binary adjacency)
                    int jb = off[j];
                    len = off[j + 1] - jb;
                    sjb[tid] = jb;
                }
            }
            int p = len;
            for (int dd = 1; dd < 64; dd <<= 1) {
                int u = __shfl_up(p, dd);
                if (lane >= dd) p += u;
            }
            spos[tid] = p - len;
            if (tid == 63) stot = p;
        }
        __syncthreads();
        const int total = stot;
        for (int q = tid; q < total; q += 256) {
            int lo = 0, hi = d - 1;
            while (lo < hi) {
                int mid = (lo + hi + 1) >> 1;
                if (spos[mid] <= q) lo = mid; else hi = mid - 1;
            }
            int t = col[sjb[lo] + (q - spos[lo])];
            if (t >= 0) {                   // skip marked entries in j's row
                unsigned bit = 1u << (t & 31);
                unsigned old = atomicOr(&acc[t >> 5], bit);
                if (old & bit) {            // duplicate 2-path: correction
                    int pos = atomicAdd(&ncorr, 1);
                    if (pos < 512) corr[pos] = (unsigned short)t;
                }
            }
        }
        __syncthreads();
    }
    // diagonal: if i reachable in 2 hops, subtract its remaining copy
    if (tid == 0) {
        if (acc[i >> 5] & (1u << (i & 31))) {
            int pos = atomicAdd(&ncorr, 1);
            if (pos < 512) corr[pos] = (unsigned short)i;
        }
    }

    // ---- t = Adj_bin @ h: gather f16 h rows over unmarked entries ----
    float a0 = 0, a1 = 0, a2 = 0, a3 = 0, a4 = 0, a5 = 0, a6 = 0, a7 = 0;
    for (int idx = rowbeg + grp; idx < rowend; idx += 16) {
        int c0 = col[idx];
        if (c0 >= 0) {
            uint4 u = hb4[(unsigned)((c0 << 4) | l16)];
            ACCM(a, u);
        }
    }
    __syncthreads();  // corr/ncorr complete

    // ---- corrections: subtract x_t for each extra 2-path occurrence ----
    {
        int nc = ncorr < 512 ? ncorr : 512;
        for (int q = grp; q < nc; q += 16) {
            int t = corr[q];
            uint4 u = xb4[(unsigned)((t << 4) | l16)];
            fmix2(a0, a1, u.x, neg1);
            fmix2(a2, a3, u.y, neg1);
            fmix2(a4, a5, u.z, neg1);
            fmix2(a6, a7, u.w, neg1);
        }
    }

    // ---- cross-group reduction: shuffle within wave, then 4-wave LDS combine ----
    RED2(a0); RED2(a1); RED2(a2); RED2(a3); RED2(a4); RED2(a5); RED2(a6); RED2(a7);
    __syncthreads();
    if (lane < 16) {
        red[wv][l16 * 8 + 0] = a0; red[wv][l16 * 8 + 1] = a1;
        red[wv][l16 * 8 + 2] = a2; red[wv][l16 * 8 + 3] = a3;
        red[wv][l16 * 8 + 4] = a4; red[wv][l16 * 8 + 5] = a5;
        red[wv][l16 * 8 + 6] = a6; red[wv][l16 * 8 + 7] = a7;
    }
    __syncthreads();
    if (tid < 128)
        agg2[(size_t)i * C + tid] = red[0][tid] + red[1][tid] + red[2][tid] + red[3][tid];
}

// ---- single-pass epilogue: 16 rows/block (750 blocks), f16 k-pair dot2 ----
__global__ __launch_bounds__(256) void epilogue(const float* __restrict__ agg1,
                                                const float* __restrict__ agg2,
                                                const unsigned* __restrict__ Wp1,
                                                const unsigned* __restrict__ Wp2,
                                                const unsigned* __restrict__ Wpf1,
                                                const unsigned* __restrict__ Wpf2,
                                                const float* __restrict__ b1,
                                                const float* __restrict__ b2,
                                                const float* __restrict__ bfused,
                                                float* __restrict__ out) {
    __shared__ unsigned shA[16][64];
    __shared__ unsigned shB[16][64];
    const int r0 = blockIdx.x * 16;
    const int tid = threadIdx.x;
    const int c0 = (tid & 63) * 2;
    const int rg = (tid >> 6) * 4;

    for (int idx = tid; idx < 512; idx += 256) {
        int r = idx >> 5, q = idx & 31;
        float4 fa = *(const float4*)&agg1[(size_t)(r0 + r) * C + q * 4];
        float4 fb = *(const float4*)&agg2[(size_t)(r0 + r) * C + q * 4];
        uint2 ua = {packh2(fa.x, fa.y), packh2(fa.z, fa.w)};
        uint2 ub = {packh2(fb.x, fb.y), packh2(fb.z, fb.w)};
        *(uint2*)&shA[r][q * 2] = ua;
        *(uint2*)&shB[r][q * 2] = ub;
    }
    __syncthreads();

    float z1v[4][2] = {}, z2v[4][2] = {}, gv[4][2] = {};
    for (int t = 0; t < 32; ++t) {
        const int k2 = t * 2;
        uint2 w1a = *(const uint2*)&Wp1[(size_t)k2 * C + c0];
        uint2 w1b = *(const uint2*)&Wp1[(size_t)(k2 + 1) * C + c0];
        uint2 w2a = *(const uint2*)&Wp2[(size_t)k2 * C + c0];
        uint2 w2b = *(const uint2*)&Wp2[(size_t)(k2 + 1) * C + c0];
        uint2 f1a = *(const uint2*)&Wpf1[(size_t)k2 * C + c0];
        uint2 f1b = *(const uint2*)&Wpf1[(size_t)(k2 + 1) * C + c0];
        uint2 f2a = *(const uint2*)&Wpf2[(size_t)k2 * C + c0];
        uint2 f2b = *(const uint2*)&Wpf2[(size_t)(k2 + 1) * C + c0];
#pragma unroll
        for (int r = 0; r < 4; ++r) {
            uint2 aA = *(const uint2*)&shA[rg + r][k2];
            uint2 aB = *(const uint2*)&shB[rg + r][k2];
            dot2acc(z1v[r][0], aA.x, w1a.x); dot2acc(z1v[r][0], aA.y, w1b.x);
            dot2acc(z1v[r][1], aA.x, w1a.y); dot2acc(z1v[r][1], aA.y, w1b.y);
            dot2acc(z2v[r][0], aB.x, w2a.x); dot2acc(z2v[r][0], aB.y, w2b.x);
            dot2acc(z2v[r][1], aB.x, w2a.y); dot2acc(z2v[r][1], aB.y, w2b.y);
            dot2acc(gv[r][0], aA.x, f1a.x);  dot2acc(gv[r][0], aA.y, f1b.x);
            dot2acc(gv[r][1], aA.x, f1a.y);  dot2acc(gv[r][1], aA.y, f1b.y);
            dot2acc(gv[r][0], aB.x, f2a.x);  dot2acc(gv[r][0], aB.y, f2b.x);
            dot2acc(gv[r][1], aB.x, f2a.y);  dot2acc(gv[r][1], aB.y, f2b.y);
        }
    }
    const float2 b1v = *(const float2*)&b1[c0];
    const float2 b2v = *(const float2*)&b2[c0];
    const float2 bfv = *(const float2*)&bfused[c0];
#pragma unroll
    for (int r = 0; r < 4; ++r) {
        float g0 = 1.f / (1.f + expf(-(gv[r][0] + bfv.x)));
        float g1 = 1.f / (1.f + expf(-(gv[r][1] + bfv.y)));
        float2 res;
        res.x = g0 * (z1v[r][0] + b1v.x) + (1.f - g0) * (z2v[r][0] + b2v.x);
        res.y = g1 * (z1v[r][1] + b1v.y) + (1.f - g1) * (z2v[r][1] + b2v.y);
        *(float2*)&out[(size_t)(r0 + rg + r) * C + c0] = res;
    }
}

extern "C" void kernel_launch(void* const* d_in, const int* in_sizes, int n_in,
                              void* d_out, int out_size, void* d_ws, size_t ws_size,
                              hipStream_t stream) {
    const float* x  = (const float*)d_in[0];
    const int*   ei = (const int*)d_in[1];
    const float* W1 = (const float*)d_in[2];
    const float* b1 = (const float*)d_in[3];
    const float* W2 = (const float*)d_in[4];
    const float* b2 = (const float*)d_in[5];
    const float* Wg = (const float*)d_in[6];
    const float* bg = (const float*)d_in[7];
    float* out = (float*)d_out;

    char* ws = (char*)d_ws;
    size_t o = 0;
    auto alloc = [&](size_t bytes) { char* p = ws + o; o = (o + bytes + 255) & ~(size_t)255; return p; };
    int* col      = (int*)alloc((size_t)NEDGE * 4);
    int* deg      = (int*)alloc((size_t)N_NODES * 2 * 4);
    int* cur      = deg + N_NODES;
    int* off      = (int*)alloc((size_t)(N_NODES + 1) * 4);
    unsigned* xb  = (unsigned*)alloc((size_t)N_NODES * C * 2);  // f16 x
    unsigned* hb  = (unsigned*)alloc((size_t)N_NODES * C * 2);  // f16 h = Adj_bin@x
    float* agg1   = (float*)alloc((size_t)N_NODES * C * 4);
    float* agg2   = (float*)alloc((size_t)N_NODES * C * 4);
    unsigned* Wp1  = (unsigned*)alloc((size_t)(C / 2) * C * 4);
    unsigned* Wp2  = (unsigned*)alloc((size_t)(C / 2) * C * 4);
    unsigned* Wpf1 = (unsigned*)alloc((size_t)(C / 2) * C * 4);
    unsigned* Wpf2 = (unsigned*)alloc((size_t)(C / 2) * C * 4);
    float* bfused  = (float*)alloc((size_t)C * 4);
    // total ~19.6 MB (proven safe)

    hipMemsetAsync(deg, 0, (size_t)N_NODES * 2 * 4, stream);

    prep_fuse<<<3128, 256, 0, stream>>>(x, xb, ei, deg, W1, W2, Wg, b1, b2, bg,
                                        Wp1, Wp2, Wpf1, Wpf2, bfused);
    scan_offsets<<<1, 1024, 0, stream>>>(deg, off);
    fill_csr<<<(NEDGE + 255) / 256, 256, 0, stream>>>(ei, off, cur, col);
    markdup_h<<<N_NODES / 4, 256, 0, stream>>>(off, col, xb, hb, agg1);
    twohop_fused<<<N_NODES, 256, 0, stream>>>(off, col, xb, hb, agg2);
    epilogue<<<N_NODES / 16, 256, 0, stream>>>(agg1, agg2, Wp1, Wp2, Wpf1, Wpf2,
                                               b1, b2, bfused, out);
}

// Round 17
// 129.716 us; speedup vs baseline: 1.5893x; 1.0071x over previous
//
#include <hip/hip_runtime.h>
#include <hip/hip_fp16.h>
#include <math.h>

#define N_NODES 12000
#define C 128
#define NEDGE 192000
#define BW 384  // u32 words per LDS dedup bitset (12288 bits >= 12000)
#define MSK 0x7FFFFFFF

// acc_lo += s*(float)f16_lo(u); acc_hi += s*(float)f16_hi(u)  -- one VOP3P each
__device__ __forceinline__ void fmix2(float& lo, float& hi, unsigned u, float s) {
    asm("v_fma_mix_f32 %0, %2, %3, %0 op_sel:[0,0,0] op_sel_hi:[1,0,0]\n\t"
        "v_fma_mix_f32 %1, %2, %3, %1 op_sel:[1,0,0] op_sel_hi:[1,0,0]"
        : "+v"(lo), "+v"(hi)
        : "v"(u), "v"(s));
}

// acc += a.lo*b.lo + a.hi*b.hi  (f16 pairs, f32 accumulate) -- one VOP3P
__device__ __forceinline__ void dot2acc(float& acc, unsigned a, unsigned b) {
    asm("v_dot2_f32_f16 %0, %1, %2, %0" : "+v"(acc) : "v"(a), "v"(b));
}

__device__ __forceinline__ unsigned packh2(float lo, float hi) {
    __half2 h = __floats2half2_rn(lo, hi);
    return *reinterpret_cast<unsigned*>(&h);
}

#define ACCM(p, u)                                            \
    fmix2(p##0, p##1, u.x, one); fmix2(p##2, p##3, u.y, one); \
    fmix2(p##4, p##5, u.z, one); fmix2(p##6, p##7, u.w, one)

#define RED2(x) x += __shfl_xor(x, 16); x += __shfl_xor(x, 32)

// ---- clear deg+cur (replaces runtime fillBuffer: 42 us observed for 96 KB) ----
__global__ __launch_bounds__(256) void clear_ws(int4* __restrict__ p) {
    p[blockIdx.x * 256 + threadIdx.x] = int4{0, 0, 0, 0};  // 24 blocks * 4 KB = 96+ KB
}

// ---- merged: x->f16 + degree hist (blocks 0..2999) | weight fuse+pack (blocks 3000..3127) ----
__global__ __launch_bounds__(256) void prep_fuse(const float* __restrict__ x,
                                                 unsigned* __restrict__ xbu,
                                                 const int* __restrict__ ei,
                                                 int* __restrict__ deg,
                                                 const float* __restrict__ W1,
                                                 const float* __restrict__ W2,
                                                 const float* __restrict__ Wg,
                                                 const float* __restrict__ b1,
                                                 const float* __restrict__ b2,
                                                 const float* __restrict__ bg,
                                                 unsigned* __restrict__ Wp1,
                                                 unsigned* __restrict__ Wp2,
                                                 unsigned* __restrict__ Wpf1,
                                                 unsigned* __restrict__ Wpf2,
                                                 float* __restrict__ bfused) {
    const int tid = threadIdx.x;
    if (blockIdx.x < 3000) {
        int g = blockIdx.x * 256 + tid;
        if (g < N_NODES * C / 2) {
            unsigned pa = __half_as_ushort(__float2half(x[2 * g]));
            unsigned pb = __half_as_ushort(__float2half(x[2 * g + 1]));
            xbu[g] = pa | (pb << 16);
        }
        if (g < NEDGE) atomicAdd(&deg[ei[g]], 1);
        return;
    }
    __shared__ __align__(16) float wg1[C];
    __shared__ __align__(16) float wg2[C];
    __shared__ float sb[C];
    __shared__ float l1[C], l2[C], lf1[C], lf2[C];
    const int c = blockIdx.x - 3000;
    const int j = tid;
    if (j < 128) {
        float g1 = Wg[(size_t)j * C + c];
        float g2 = Wg[(size_t)(C + j) * C + c];
        wg1[j] = g1;
        wg2[j] = g2;
        sb[j] = b1[j] * g1 + b2[j] * g2;
    }
    __syncthreads();
    if (j < 128) {
        float s1 = 0.f, s2 = 0.f;
        for (int k = 0; k < C; k += 4) {
            float4 a = *(const float4*)&W1[(size_t)j * C + k];
            float4 b = *(const float4*)&W2[(size_t)j * C + k];
            float4 u = *(const float4*)&wg1[k];
            float4 v = *(const float4*)&wg2[k];
            s1 += a.x * u.x + a.y * u.y + a.z * u.z + a.w * u.w;
            s2 += b.x * v.x + b.y * v.y + b.z * v.z + b.w * v.w;
        }
        l1[j] = W1[(size_t)j * C + c];
        l2[j] = W2[(size_t)j * C + c];
        lf1[j] = s1;
        lf2[j] = s2;
    }
    __syncthreads();
    if (j < 64) {
        Wp1[(size_t)j * C + c]  = packh2(l1[2 * j], l1[2 * j + 1]);
        Wp2[(size_t)j * C + c]  = packh2(l2[2 * j], l2[2 * j + 1]);
        Wpf1[(size_t)j * C + c] = packh2(lf1[2 * j], lf1[2 * j + 1]);
        Wpf2[(size_t)j * C + c] = packh2(lf2[2 * j], lf2[2 * j + 1]);
    }
    if (j == 0) {
        float s = bg[c];
        for (int k = 0; k < C; ++k) s += sb[k];
        bfused[c] = s;
    }
}

// ---- exclusive scan of degrees -> CSR offsets (single 1024-thread block) ----
__global__ __launch_bounds__(1024) void scan_offsets(const int* __restrict__ deg,
                                                     int* __restrict__ off) {
    __shared__ int wsum[16];
    const int t = threadIdx.x;
    const int lane = t & 63, wv = t >> 6;
    const int PER = 12;
    const int lo = t * PER;
    int local[PER];
    int sum = 0;
#pragma unroll
    for (int k = 0; k < PER; ++k) {
        int i = lo + k;
        int d = (i < N_NODES) ? deg[i] : 0;
        local[k] = sum;
        sum += d;
    }
    int p = sum;
    for (int d = 1; d < 64; d <<= 1) {
        int u = __shfl_up(p, d);
        if (lane >= d) p += u;
    }
    if (lane == 63) wsum[wv] = p;
    __syncthreads();
    int wbase = 0;
    for (int k = 0; k < wv; ++k) wbase += wsum[k];
    const int tbase = wbase + p - sum;
#pragma unroll
    for (int k = 0; k < PER; ++k) {
        int i = lo + k;
        if (i < N_NODES) off[i] = tbase + local[k];
    }
    if (t == 0) off[N_NODES] = NEDGE;
}

// ---- fill CSR columns (order within row irrelevant; duplicates kept) ----
__global__ void fill_csr(const int* __restrict__ ei, const int* __restrict__ off,
                         int* __restrict__ cur, int* __restrict__ col) {
    int e = blockIdx.x * blockDim.x + threadIdx.x;
    if (e >= NEDGE) return;
    int s = ei[e];
    int t = ei[NEDGE + e];
    int pos = atomicAdd(&cur[s], 1);
    col[off[s] + pos] = t;
}

// ---- mark dup edges (sign bit) + h(dedup, f16 out) + agg1(multiplicity, fp32 out) ----
__global__ __launch_bounds__(256) void markdup_h(const int* __restrict__ off,
                                                 int* __restrict__ col,
                                                 const unsigned* __restrict__ xb,
                                                 unsigned* __restrict__ hb,
                                                 float* __restrict__ agg1) {
    __shared__ int rows[4][256];
    const int tid = threadIdx.x;
    const int lane = tid & 63, wv = tid >> 6;
    const int i = blockIdx.x * 4 + wv;
    const int rb = off[i], re = off[i + 1];
    const int d = re - rb;
    const int dc = d < 256 ? d : 256;
    const uint4* xb4 = (const uint4*)xb;
    const float one = 1.0f;

    for (int e = lane; e < dc; e += 64) rows[wv][e] = col[rb + e];
    for (int e = lane; e < dc; e += 64) {
        int vm = rows[wv][e] & MSK;
        bool dup = false;
        for (int e2 = 0; e2 < e; ++e2)
            if ((rows[wv][e2] & MSK) == vm) { dup = true; break; }
        if (dup) {
            rows[wv][e] = vm | 0x80000000;
            col[rb + e] = vm | 0x80000000;   // visible to next dispatch
        }
    }
    __syncthreads();

    const int g = lane >> 4, l16 = lane & 15;
    float a0 = 0, a1 = 0, a2 = 0, a3 = 0, a4 = 0, a5 = 0, a6 = 0, a7 = 0;
    float b0 = 0, b1 = 0, b2 = 0, b3 = 0, b4 = 0, b5 = 0, b6 = 0, b7 = 0;
    for (int e = g; e < d; e += 4) {
        int c0 = (e < 256) ? rows[wv][e] : col[rb + e];
        int k = c0 & MSK;
        uint4 u = xb4[(unsigned)((k << 4) | l16)];
        ACCM(b, u);
        if (c0 >= 0) { ACCM(a, u); }
    }
    RED2(a0); RED2(a1); RED2(a2); RED2(a3); RED2(a4); RED2(a5); RED2(a6); RED2(a7);
    RED2(b0); RED2(b1); RED2(b2); RED2(b3); RED2(b4); RED2(b5); RED2(b6); RED2(b7);
    if (lane < 16) {
        uint4 hp = {packh2(a0, a1), packh2(a2, a3), packh2(a4, a5), packh2(a6, a7)};
        ((uint4*)hb)[(unsigned)((i << 4) | l16)] = hp;
        float4 w0 = {b0, b1, b2, b3}, w1 = {b4, b5, b6, b7};
        *(float4*)&agg1[(size_t)i * C + l16 * 8] = w0;
        *(float4*)&agg1[(size_t)i * C + l16 * 8 + 4] = w1;
    }
}

// ---- fused: union + test-and-set corrections + agg2 = Adj_bin@h - corrections ----
__global__ __launch_bounds__(256) void twohop_fused(const int* __restrict__ off,
                                                    const int* __restrict__ col,
                                                    const unsigned* __restrict__ xb,
                                                    const unsigned* __restrict__ hb,
                                                    float* __restrict__ agg2) {
    __shared__ unsigned acc[BW];
    __shared__ int sjb[64];
    __shared__ int spos[64];
    __shared__ int stot;
    __shared__ int ncorr;
    __shared__ unsigned short corr[512];
    __shared__ float red[4][128];
    const int i = blockIdx.x;
    const int tid = threadIdx.x;
    const int lane = tid & 63;
    const int wv = tid >> 6;
    const int grp = tid >> 4, l16 = tid & 15;
    const int rowbeg = off[i], rowend = off[i + 1];
    const uint4* xb4 = (const uint4*)xb;
    const uint4* hb4 = (const uint4*)hb;
    const float one = 1.0f, neg1 = -1.0f;

    for (int w = tid; w < BW; w += 256) acc[w] = 0u;
    if (tid == 0) ncorr = 0;
    __syncthreads();

    for (int base = rowbeg; base < rowend; base += 64) {
        int d = rowend - base;
        if (d > 64) d = 64;
        if (tid < 64) {
            int len = 0;
            if (tid < d) {
                int j = col[base + tid];
                if (j >= 0) {
                    int jb = off[j];
                    len = off[j + 1] - jb;
                    sjb[tid] = jb;
                }
            }
            int p = len;
            for (int dd = 1; dd < 64; dd <<= 1) {
                int u = __shfl_up(p, dd);
                if (lane >= dd) p += u;
            }
            spos[tid] = p - len;
            if (tid == 63) stot = p;
        }
        __syncthreads();
        const int total = stot;
        for (int q = tid; q < total; q += 256) {
            int lo = 0, hi = d - 1;
            while (lo < hi) {
                int mid = (lo + hi + 1) >> 1;
                if (spos[mid] <= q) lo = mid; else hi = mid - 1;
            }
            int t = col[sjb[lo] + (q - spos[lo])];
            if (t >= 0) {
                unsigned bit = 1u << (t & 31);
                unsigned old = atomicOr(&acc[t >> 5], bit);
                if (old & bit) {
                    int pos = atomicAdd(&ncorr, 1);
                    if (pos < 512) corr[pos] = (unsigned short)t;
                }
            }
        }
        __syncthreads();
    }
    if (tid == 0) {
        if (acc[i >> 5] & (1u << (i & 31))) {
            int pos = atomicAdd(&ncorr, 1);
            if (pos < 512) corr[pos] = (unsigned short)i;
        }
    }

    float a0 = 0, a1 = 0, a2 = 0, a3 = 0, a4 = 0, a5 = 0, a6 = 0, a7 = 0;
    for (int idx = rowbeg + grp; idx < rowend; idx += 16) {
        int c0 = col[idx];
        if (c0 >= 0) {
            uint4 u = hb4[(unsigned)((c0 << 4) | l16)];
            ACCM(a, u);
        }
    }
    __syncthreads();

    {
        int nc = ncorr < 512 ? ncorr : 512;
        for (int q = grp; q < nc; q += 16) {
            int t = corr[q];
            uint4 u = xb4[(unsigned)((t << 4) | l16)];
            fmix2(a0, a1, u.x, neg1);
            fmix2(a2, a3, u.y, neg1);
            fmix2(a4, a5, u.z, neg1);
            fmix2(a6, a7, u.w, neg1);
        }
    }

    RED2(a0); RED2(a1); RED2(a2); RED2(a3); RED2(a4); RED2(a5); RED2(a6); RED2(a7);
    __syncthreads();
    if (lane < 16) {
        red[wv][l16 * 8 + 0] = a0; red[wv][l16 * 8 + 1] = a1;
        red[wv][l16 * 8 + 2] = a2; red[wv][l16 * 8 + 3] = a3;
        red[wv][l16 * 8 + 4] = a4; red[wv][l16 * 8 + 5] = a5;
        red[wv][l16 * 8 + 6] = a6; red[wv][l16 * 8 + 7] = a7;
    }
    __syncthreads();
    if (tid < 128)
        agg2[(size_t)i * C + tid] = red[0][tid] + red[1][tid] + red[2][tid] + red[3][tid];
}

// ---- single-pass epilogue: 16 rows/block (750 blocks), f16 k-pair dot2 ----
__global__ __launch_bounds__(256) void epilogue(const float* __restrict__ agg1,
                                                const float* __restrict__ agg2,
                                                const unsigned* __restrict__ Wp1,
                                                const unsigned* __restrict__ Wp2,
                                                const unsigned* __restrict__ Wpf1,
                                                const unsigned* __restrict__ Wpf2,
                                                const float* __restrict__ b1,
                                                const float* __restrict__ b2,
                                                const float* __restrict__ bfused,
                                                float* __restrict__ out) {
    __shared__ unsigned shA[16][64];
    __shared__ unsigned shB[16][64];
    const int r0 = blockIdx.x * 16;
    const int tid = threadIdx.x;
    const int c0 = (tid & 63) * 2;
    const int rg = (tid >> 6) * 4;

    for (int idx = tid; idx < 512; idx += 256) {
        int r = idx >> 5, q = idx & 31;
        float4 fa = *(const float4*)&agg1[(size_t)(r0 + r) * C + q * 4];
        float4 fb = *(const float4*)&agg2[(size_t)(r0 + r) * C + q * 4];
        uint2 ua = {packh2(fa.x, fa.y), packh2(fa.z, fa.w)};
        uint2 ub = {packh2(fb.x, fb.y), packh2(fb.z, fb.w)};
        *(uint2*)&shA[r][q * 2] = ua;
        *(uint2*)&shB[r][q * 2] = ub;
    }
    __syncthreads();

    float z1v[4][2] = {}, z2v[4][2] = {}, gv[4][2] = {};
    for (int t = 0; t < 32; ++t) {
        const int k2 = t * 2;
        uint2 w1a = *(const uint2*)&Wp1[(size_t)k2 * C + c0];
        uint2 w1b = *(const uint2*)&Wp1[(size_t)(k2 + 1) * C + c0];
        uint2 w2a = *(const uint2*)&Wp2[(size_t)k2 * C + c0];
        uint2 w2b = *(const uint2*)&Wp2[(size_t)(k2 + 1) * C + c0];
        uint2 f1a = *(const uint2*)&Wpf1[(size_t)k2 * C + c0];
        uint2 f1b = *(const uint2*)&Wpf1[(size_t)(k2 + 1) * C + c0];
        uint2 f2a = *(const uint2*)&Wpf2[(size_t)k2 * C + c0];
        uint2 f2b = *(const uint2*)&Wpf2[(size_t)(k2 + 1) * C + c0];
#pragma unroll
        for (int r = 0; r < 4; ++r) {
            uint2 aA = *(const uint2*)&shA[rg + r][k2];
            uint2 aB = *(const uint2*)&shB[rg + r][k2];
            dot2acc(z1v[r][0], aA.x, w1a.x); dot2acc(z1v[r][0], aA.y, w1b.x);
            dot2acc(z1v[r][1], aA.x, w1a.y); dot2acc(z1v[r][1], aA.y, w1b.y);
            dot2acc(z2v[r][0], aB.x, w2a.x); dot2acc(z2v[r][0], aB.y, w2b.x);
            dot2acc(z2v[r][1], aB.x, w2a.y); dot2acc(z2v[r][1], aB.y, w2b.y);
            dot2acc(gv[r][0], aA.x, f1a.x);  dot2acc(gv[r][0], aA.y, f1b.x);
            dot2acc(gv[r][1], aA.x, f1a.y);  dot2acc(gv[r][1], aA.y, f1b.y);
            dot2acc(gv[r][0], aB.x, f2a.x);  dot2acc(gv[r][0], aB.y, f2b.x);
            dot2acc(gv[r][1], aB.x, f2a.y);  dot2acc(gv[r][1], aB.y, f2b.y);
        }
    }
    const float2 b1v = *(const float2*)&b1[c0];
    const float2 b2v = *(const float2*)&b2[c0];
    const float2 bfv = *(const float2*)&bfused[c0];
#pragma unroll
    for (int r = 0; r < 4; ++r) {
        float g0 = 1.f / (1.f + expf(-(gv[r][0] + bfv.x)));
        float g1 = 1.f / (1.f + expf(-(gv[r][1] + bfv.y)));
        float2 res;
        res.x = g0 * (z1v[r][0] + b1v.x) + (1.f - g0) * (z2v[r][0] + b2v.x);
        res.y = g1 * (z1v[r][1] + b1v.y) + (1.f - g1) * (z2v[r][1] + b2v.y);
        *(float2*)&out[(size_t)(r0 + rg + r) * C + c0] = res;
    }
}

extern "C" void kernel_launch(void* const* d_in, const int* in_sizes, int n_in,
                              void* d_out, int out_size, void* d_ws, size_t ws_size,
                              hipStream_t stream) {
    const float* x  = (const float*)d_in[0];
    const int*   ei = (const int*)d_in[1];
    const float* W1 = (const float*)d_in[2];
    const float* b1 = (const float*)d_in[3];
    const float* W2 = (const float*)d_in[4];
    const float* b2 = (const float*)d_in[5];
    const float* Wg = (const float*)d_in[6];
    const float* bg = (const float*)d_in[7];
    float* out = (float*)d_out;

    char* ws = (char*)d_ws;
    size_t o = 0;
    auto alloc = [&](size_t bytes) { char* p = ws + o; o = (o + bytes + 255) & ~(size_t)255; return p; };
    int* col      = (int*)alloc((size_t)NEDGE * 4);
    int* deg      = (int*)alloc((size_t)24576 * 4);   // deg[12000] + cur[12000], 16B-aligned pad
    int* cur      = deg + N_NODES;
    int* off      = (int*)alloc((size_t)(N_NODES + 1) * 4);
    unsigned* xb  = (unsigned*)alloc((size_t)N_NODES * C * 2);  // f16 x
    unsigned* hb  = (unsigned*)alloc((size_t)N_NODES * C * 2);  // f16 h = Adj_bin@x
    float* agg1   = (float*)alloc((size_t)N_NODES * C * 4);
    float* agg2   = (float*)alloc((size_t)N_NODES * C * 4);
    unsigned* Wp1  = (unsigned*)alloc((size_t)(C / 2) * C * 4);
    unsigned* Wp2  = (unsigned*)alloc((size_t)(C / 2) * C * 4);
    unsigned* Wpf1 = (unsigned*)alloc((size_t)(C / 2) * C * 4);
    unsigned* Wpf2 = (unsigned*)alloc((size_t)(C / 2) * C * 4);
    float* bfused  = (float*)alloc((size_t)C * 4);
    // total ~19.6 MB (proven safe)

    clear_ws<<<24, 256, 0, stream>>>((int4*)deg);  // 24*256*16B = 98304 B >= 24000 ints
    prep_fuse<<<3128, 256, 0, stream>>>(x, xb, ei, deg, W1, W2, Wg, b1, b2, bg,
                                        Wp1, Wp2, Wpf1, Wpf2, bfused);
    scan_offsets<<<1, 1024, 0, stream>>>(deg, off);
    fill_csr<<<(NEDGE + 255) / 256, 256, 0, stream>>>(ei, off, cur, col);
    markdup_h<<<N_NODES / 4, 256, 0, stream>>>(off, col, xb, hb, agg1);
    twohop_fused<<<N_NODES, 256, 0, stream>>>(off, col, xb, hb, agg2);
    epilogue<<<N_NODES / 16, 256, 0, stream>>>(agg1, agg2, Wp1, Wp2, Wpf1, Wpf2,
                                               b1, b2, bfused, out);
}

// Round 18
// 111.218 us; speedup vs baseline: 1.8537x; 1.1663x over previous
//
#include <hip/hip_runtime.h>
#include <hip/hip_fp16.h>
#include <math.h>

#define N_NODES 12000
#define C 128
#define NEDGE 192000
#define BW 384  // u32 words per LDS dedup bitset (12288 bits >= 12000)
#define MSK 0x7FFFFFFF
#define ELL 64  // ELL row stride; max degree ~45 (Binom(192000,1/12000)), P(>64)~1e-20

// acc_lo += s*(float)f16_lo(u); acc_hi += s*(float)f16_hi(u)  -- one VOP3P each
__device__ __forceinline__ void fmix2(float& lo, float& hi, unsigned u, float s) {
    asm("v_fma_mix_f32 %0, %2, %3, %0 op_sel:[0,0,0] op_sel_hi:[1,0,0]\n\t"
        "v_fma_mix_f32 %1, %2, %3, %1 op_sel:[1,0,0] op_sel_hi:[1,0,0]"
        : "+v"(lo), "+v"(hi)
        : "v"(u), "v"(s));
}

// acc += a.lo*b.lo + a.hi*b.hi  (f16 pairs, f32 accumulate) -- one VOP3P
__device__ __forceinline__ void dot2acc(float& acc, unsigned a, unsigned b) {
    asm("v_dot2_f32_f16 %0, %1, %2, %0" : "+v"(acc) : "v"(a), "v"(b));
}

__device__ __forceinline__ unsigned packh2(float lo, float hi) {
    __half2 h = __floats2half2_rn(lo, hi);
    return *reinterpret_cast<unsigned*>(&h);
}

#define ACCM(p, u)                                            \
    fmix2(p##0, p##1, u.x, one); fmix2(p##2, p##3, u.y, one); \
    fmix2(p##4, p##5, u.z, one); fmix2(p##6, p##7, u.w, one)

#define RED2(x) x += __shfl_xor(x, 16); x += __shfl_xor(x, 32)

// ---- zero deg[12288] (12 blocks * 256 * int4 = 49152 B) ----
__global__ __launch_bounds__(256) void clear_ws(int4* __restrict__ p) {
    p[blockIdx.x * 256 + threadIdx.x] = int4{0, 0, 0, 0};
}

// ---- merged: x->f16 + ELL edge scatter (blocks 0..2999) | weight fuse+pack (3000..3127) ----
__global__ __launch_bounds__(256) void prep_fuse(const float* __restrict__ x,
                                                 unsigned* __restrict__ xbu,
                                                 const int* __restrict__ ei,
                                                 int* __restrict__ deg,
                                                 int* __restrict__ col,
                                                 const float* __restrict__ W1,
                                                 const float* __restrict__ W2,
                                                 const float* __restrict__ Wg,
                                                 const float* __restrict__ b1,
                                                 const float* __restrict__ b2,
                                                 const float* __restrict__ bg,
                                                 unsigned* __restrict__ Wp1,
                                                 unsigned* __restrict__ Wp2,
                                                 unsigned* __restrict__ Wpf1,
                                                 unsigned* __restrict__ Wpf2,
                                                 float* __restrict__ bfused) {
    const int tid = threadIdx.x;
    if (blockIdx.x < 3000) {
        int g = blockIdx.x * 256 + tid;
        if (g < N_NODES * C / 2) {
            unsigned pa = __half_as_ushort(__float2half(x[2 * g]));
            unsigned pb = __half_as_ushort(__float2half(x[2 * g + 1]));
            xbu[g] = pa | (pb << 16);
        }
        if (g < NEDGE) {
            int s = ei[g];
            int t = ei[NEDGE + g];
            int pos = atomicAdd(&deg[s], 1);
            col[(s << 6) + pos] = t;
        }
        return;
    }
    __shared__ __align__(16) float wg1[C];
    __shared__ __align__(16) float wg2[C];
    __shared__ float sb[C];
    __shared__ float l1[C], l2[C], lf1[C], lf2[C];
    const int c = blockIdx.x - 3000;
    const int j = tid;
    if (j < 128) {
        float g1 = Wg[(size_t)j * C + c];
        float g2 = Wg[(size_t)(C + j) * C + c];
        wg1[j] = g1;
        wg2[j] = g2;
        sb[j] = b1[j] * g1 + b2[j] * g2;
    }
    __syncthreads();
    if (j < 128) {
        float s1 = 0.f, s2 = 0.f;
        for (int k = 0; k < C; k += 4) {
            float4 a = *(const float4*)&W1[(size_t)j * C + k];
            float4 b = *(const float4*)&W2[(size_t)j * C + k];
            float4 u = *(const float4*)&wg1[k];
            float4 v = *(const float4*)&wg2[k];
            s1 += a.x * u.x + a.y * u.y + a.z * u.z + a.w * u.w;
            s2 += b.x * v.x + b.y * v.y + b.z * v.z + b.w * v.w;
        }
        l1[j] = W1[(size_t)j * C + c];
        l2[j] = W2[(size_t)j * C + c];
        lf1[j] = s1;
        lf2[j] = s2;
    }
    __syncthreads();
    if (j < 64) {
        Wp1[(size_t)j * C + c]  = packh2(l1[2 * j], l1[2 * j + 1]);
        Wp2[(size_t)j * C + c]  = packh2(l2[2 * j], l2[2 * j + 1]);
        Wpf1[(size_t)j * C + c] = packh2(lf1[2 * j], lf1[2 * j + 1]);
        Wpf2[(size_t)j * C + c] = packh2(lf2[2 * j], lf2[2 * j + 1]);
    }
    if (j == 0) {
        float s = bg[c];
        for (int k = 0; k < C; ++k) s += sb[k];
        bfused[c] = s;
    }
}

// ---- mark dup edges (sign bit) + h(dedup, f16 out) + agg1(multiplicity, fp32 out) ----
// One wave per node (ELL row, d <= 64); both aggregates share the same xb row loads.
__global__ __launch_bounds__(256) void markdup_h(const int* __restrict__ deg,
                                                 int* __restrict__ col,
                                                 const unsigned* __restrict__ xb,
                                                 unsigned* __restrict__ hb,
                                                 float* __restrict__ agg1) {
    __shared__ int rows[4][ELL];
    const int tid = threadIdx.x;
    const int lane = tid & 63, wv = tid >> 6;
    const int i = blockIdx.x * 4 + wv;
    const int rb = i << 6;
    const int d = deg[i];
    const uint4* xb4 = (const uint4*)xb;
    const float one = 1.0f;

    if (lane < d) rows[wv][lane] = col[rb + lane];
    if (lane < d) {
        int vm = rows[wv][lane] & MSK;
        bool dup = false;
        for (int e2 = 0; e2 < lane; ++e2)
            if ((rows[wv][e2] & MSK) == vm) { dup = true; break; }
        if (dup) {
            rows[wv][lane] = vm | 0x80000000;
            col[rb + lane] = vm | 0x80000000;   // visible to next dispatch
        }
    }
    __syncthreads();

    const int g = lane >> 4, l16 = lane & 15;
    float a0 = 0, a1 = 0, a2 = 0, a3 = 0, a4 = 0, a5 = 0, a6 = 0, a7 = 0;
    float b0 = 0, b1 = 0, b2 = 0, b3 = 0, b4 = 0, b5 = 0, b6 = 0, b7 = 0;
    for (int e = g; e < d; e += 4) {
        int c0 = rows[wv][e];
        int k = c0 & MSK;
        uint4 u = xb4[(unsigned)((k << 4) | l16)];
        ACCM(b, u);
        if (c0 >= 0) { ACCM(a, u); }
    }
    RED2(a0); RED2(a1); RED2(a2); RED2(a3); RED2(a4); RED2(a5); RED2(a6); RED2(a7);
    RED2(b0); RED2(b1); RED2(b2); RED2(b3); RED2(b4); RED2(b5); RED2(b6); RED2(b7);
    if (lane < 16) {
        uint4 hp = {packh2(a0, a1), packh2(a2, a3), packh2(a4, a5), packh2(a6, a7)};
        ((uint4*)hb)[(unsigned)((i << 4) | l16)] = hp;
        float4 w0 = {b0, b1, b2, b3}, w1 = {b4, b5, b6, b7};
        *(float4*)&agg1[(size_t)i * C + l16 * 8] = w0;
        *(float4*)&agg1[(size_t)i * C + l16 * 8 + 4] = w1;
    }
}

// ---- fused: union (single ELL chunk) + test-and-set corrections + agg2 ----
__global__ __launch_bounds__(256) void twohop_fused(const int* __restrict__ deg,
                                                    const int* __restrict__ col,
                                                    const unsigned* __restrict__ xb,
                                                    const unsigned* __restrict__ hb,
                                                    float* __restrict__ agg2) {
    __shared__ unsigned acc[BW];
    __shared__ int sjb[64];
    __shared__ int spos[64];
    __shared__ int stot;
    __shared__ int ncorr;
    __shared__ unsigned short corr[512];
    __shared__ float red[4][128];
    const int i = blockIdx.x;
    const int tid = threadIdx.x;
    const int lane = tid & 63;
    const int wv = tid >> 6;
    const int grp = tid >> 4, l16 = tid & 15;
    const int rb = i << 6;
    const int d = deg[i];
    const uint4* xb4 = (const uint4*)xb;
    const uint4* hb4 = (const uint4*)hb;
    const float one = 1.0f, neg1 = -1.0f;

    for (int w = tid; w < BW; w += 256) acc[w] = 0u;
    if (tid == 0) ncorr = 0;
    __syncthreads();

    // ---- union: single chunk (d <= 64), flattened candidates ----
    if (tid < 64) {
        int len = 0;
        if (tid < d) {
            int j = col[rb + tid];
            if (j >= 0) {               // skip duplicate edges (binary adjacency)
                len = deg[j];
                sjb[tid] = j << 6;
            }
        }
        int p = len;
        for (int dd = 1; dd < 64; dd <<= 1) {
            int u = __shfl_up(p, dd);
            if (lane >= dd) p += u;
        }
        spos[tid] = p - len;
        if (tid == 63) stot = p;
    }
    __syncthreads();
    {
        const int total = stot;
        for (int q = tid; q < total; q += 256) {
            int lo = 0, hi = d - 1;
            while (lo < hi) {
                int mid = (lo + hi + 1) >> 1;
                if (spos[mid] <= q) lo = mid; else hi = mid - 1;
            }
            int t = col[sjb[lo] + (q - spos[lo])];
            if (t >= 0) {               // skip marked entries in j's row
                unsigned bit = 1u << (t & 31);
                unsigned old = atomicOr(&acc[t >> 5], bit);
                if (old & bit) {        // duplicate 2-path: correction
                    int pos = atomicAdd(&ncorr, 1);
                    if (pos < 512) corr[pos] = (unsigned short)t;
                }
            }
        }
    }
    __syncthreads();
    // diagonal: if i reachable in 2 hops, subtract its remaining copy
    if (tid == 0) {
        if (acc[i >> 5] & (1u << (i & 31))) {
            int pos = atomicAdd(&ncorr, 1);
            if (pos < 512) corr[pos] = (unsigned short)i;
        }
    }

    // ---- t = Adj_bin @ h: gather f16 h rows over unmarked entries ----
    float a0 = 0, a1 = 0, a2 = 0, a3 = 0, a4 = 0, a5 = 0, a6 = 0, a7 = 0;
    for (int e = grp; e < d; e += 16) {
        int c0 = col[rb + e];
        if (c0 >= 0) {
            uint4 u = hb4[(unsigned)((c0 << 4) | l16)];
            ACCM(a, u);
        }
    }
    __syncthreads();  // corr/ncorr complete

    // ---- corrections: subtract x_t for each extra 2-path occurrence ----
    {
        int nc = ncorr < 512 ? ncorr : 512;
        for (int q = grp; q < nc; q += 16) {
            int t = corr[q];
            uint4 u = xb4[(unsigned)((t << 4) | l16)];
            fmix2(a0, a1, u.x, neg1);
            fmix2(a2, a3, u.y, neg1);
            fmix2(a4, a5, u.z, neg1);
            fmix2(a6, a7, u.w, neg1);
        }
    }

    RED2(a0); RED2(a1); RED2(a2); RED2(a3); RED2(a4); RED2(a5); RED2(a6); RED2(a7);
    __syncthreads();
    if (lane < 16) {
        red[wv][l16 * 8 + 0] = a0; red[wv][l16 * 8 + 1] = a1;
        red[wv][l16 * 8 + 2] = a2; red[wv][l16 * 8 + 3] = a3;
        red[wv][l16 * 8 + 4] = a4; red[wv][l16 * 8 + 5] = a5;
        red[wv][l16 * 8 + 6] = a6; red[wv][l16 * 8 + 7] = a7;
    }
    __syncthreads();
    if (tid < 128)
        agg2[(size_t)i * C + tid] = red[0][tid] + red[1][tid] + red[2][tid] + red[3][tid];
}

// ---- single-pass epilogue: 16 rows/block (750 blocks), f16 k-pair dot2 ----
__global__ __launch_bounds__(256) void epilogue(const float* __restrict__ agg1,
                                                const float* __restrict__ agg2,
                                                const unsigned* __restrict__ Wp1,
                                                const unsigned* __restrict__ Wp2,
                                                const unsigned* __restrict__ Wpf1,
                                                const unsigned* __restrict__ Wpf2,
                                                const float* __restrict__ b1,
                                                const float* __restrict__ b2,
                                                const float* __restrict__ bfused,
                                                float* __restrict__ out) {
    __shared__ unsigned shA[16][64];
    __shared__ unsigned shB[16][64];
    const int r0 = blockIdx.x * 16;
    const int tid = threadIdx.x;
    const int c0 = (tid & 63) * 2;
    const int rg = (tid >> 6) * 4;

    for (int idx = tid; idx < 512; idx += 256) {
        int r = idx >> 5, q = idx & 31;
        float4 fa = *(const float4*)&agg1[(size_t)(r0 + r) * C + q * 4];
        float4 fb = *(const float4*)&agg2[(size_t)(r0 + r) * C + q * 4];
        uint2 ua = {packh2(fa.x, fa.y), packh2(fa.z, fa.w)};
        uint2 ub = {packh2(fb.x, fb.y), packh2(fb.z, fb.w)};
        *(uint2*)&shA[r][q * 2] = ua;
        *(uint2*)&shB[r][q * 2] = ub;
    }
    __syncthreads();

    float z1v[4][2] = {}, z2v[4][2] = {}, gv[4][2] = {};
    for (int t = 0; t < 32; ++t) {
        const int k2 = t * 2;
        uint2 w1a = *(const uint2*)&Wp1[(size_t)k2 * C + c0];
        uint2 w1b = *(const uint2*)&Wp1[(size_t)(k2 + 1) * C + c0];
        uint2 w2a = *(const uint2*)&Wp2[(size_t)k2 * C + c0];
        uint2 w2b = *(const uint2*)&Wp2[(size_t)(k2 + 1) * C + c0];
        uint2 f1a = *(const uint2*)&Wpf1[(size_t)k2 * C + c0];
        uint2 f1b = *(const uint2*)&Wpf1[(size_t)(k2 + 1) * C + c0];
        uint2 f2a = *(const uint2*)&Wpf2[(size_t)k2 * C + c0];
        uint2 f2b = *(const uint2*)&Wpf2[(size_t)(k2 + 1) * C + c0];
#pragma unroll
        for (int r = 0; r < 4; ++r) {
            uint2 aA = *(const uint2*)&shA[rg + r][k2];
            uint2 aB = *(const uint2*)&shB[rg + r][k2];
            dot2acc(z1v[r][0], aA.x, w1a.x); dot2acc(z1v[r][0], aA.y, w1b.x);
            dot2acc(z1v[r][1], aA.x, w1a.y); dot2acc(z1v[r][1], aA.y, w1b.y);
            dot2acc(z2v[r][0], aB.x, w2a.x); dot2acc(z2v[r][0], aB.y, w2b.x);
            dot2acc(z2v[r][1], aB.x, w2a.y); dot2acc(z2v[r][1], aB.y, w2b.y);
            dot2acc(gv[r][0], aA.x, f1a.x);  dot2acc(gv[r][0], aA.y, f1b.x);
            dot2acc(gv[r][1], aA.x, f1a.y);  dot2acc(gv[r][1], aA.y, f1b.y);
            dot2acc(gv[r][0], aB.x, f2a.x);  dot2acc(gv[r][0], aB.y, f2b.x);
            dot2acc(gv[r][1], aB.x, f2a.y);  dot2acc(gv[r][1], aB.y, f2b.y);
        }
    }
    const float2 b1v = *(const float2*)&b1[c0];
    const float2 b2v = *(const float2*)&b2[c0];
    const float2 bfv = *(const float2*)&bfused[c0];
#pragma unroll
    for (int r = 0; r < 4; ++r) {
        float g0 = 1.f / (1.f + expf(-(gv[r][0] + bfv.x)));
        float g1 = 1.f / (1.f + expf(-(gv[r][1] + bfv.y)));
        float2 res;
        res.x = g0 * (z1v[r][0] + b1v.x) + (1.f - g0) * (z2v[r][0] + b2v.x);
        res.y = g1 * (z1v[r][1] + b1v.y) + (1.f - g1) * (z2v[r][1] + b2v.y);
        *(float2*)&out[(size_t)(r0 + rg + r) * C + c0] = res;
    }
}

extern "C" void kernel_launch(void* const* d_in, const int* in_sizes, int n_in,
                              void* d_out, int out_size, void* d_ws, size_t ws_size,
                              hipStream_t stream) {
    const float* x  = (const float*)d_in[0];
    const int*   ei = (const int*)d_in[1];
    const float* W1 = (const float*)d_in[2];
    const float* b1 = (const float*)d_in[3];
    const float* W2 = (const float*)d_in[4];
    const float* b2 = (const float*)d_in[5];
    const float* Wg = (const float*)d_in[6];
    const float* bg = (const float*)d_in[7];
    float* out = (float*)d_out;

    char* ws = (char*)d_ws;
    size_t o = 0;
    auto alloc = [&](size_t bytes) { char* p = ws + o; o = (o + bytes + 255) & ~(size_t)255; return p; };
    int* col      = (int*)alloc((size_t)N_NODES * ELL * 4);     // 3 MB ELL
    int* deg      = (int*)alloc((size_t)12288 * 4);             // cleared region (49152 B)
    unsigned* xb  = (unsigned*)alloc((size_t)N_NODES * C * 2);  // f16 x
    unsigned* hb  = (unsigned*)alloc((size_t)N_NODES * C * 2);  // f16 h = Adj_bin@x
    float* agg1   = (float*)alloc((size_t)N_NODES * C * 4);
    float* agg2   = (float*)alloc((size_t)N_NODES * C * 4);
    unsigned* Wp1  = (unsigned*)alloc((size_t)(C / 2) * C * 4);
    unsigned* Wp2  = (unsigned*)alloc((size_t)(C / 2) * C * 4);
    unsigned* Wpf1 = (unsigned*)alloc((size_t)(C / 2) * C * 4);
    unsigned* Wpf2 = (unsigned*)alloc((size_t)(C / 2) * C * 4);
    float* bfused  = (float*)alloc((size_t)C * 4);
    // total ~21.7 MB (proven safe)

    clear_ws<<<12, 256, 0, stream>>>((int4*)deg);  // 12*256*16B = 49152 B >= 12288 ints
    prep_fuse<<<3128, 256, 0, stream>>>(x, xb, ei, deg, col, W1, W2, Wg, b1, b2, bg,
                                        Wp1, Wp2, Wpf1, Wpf2, bfused);
    markdup_h<<<N_NODES / 4, 256, 0, stream>>>(deg, col, xb, hb, agg1);
    twohop_fused<<<N_NODES, 256, 0, stream>>>(deg, col, xb, hb, agg2);
    epilogue<<<N_NODES / 16, 256, 0, stream>>>(agg1, agg2, Wp1, Wp2, Wpf1, Wpf2,
                                               b1, b2, bfused, out);
}

// Round 20
// 103.311 us; speedup vs baseline: 1.9955x; 1.0765x over previous
//
#include <hip/hip_runtime.h>
#include <hip/hip_fp16.h>
#include <math.h>

#define N_NODES 12000
#define C 128
#define NEDGE 192000
#define BW 384  // u32 words per dedup bitset (12288 bits >= 12000)
#define MSK 0x7FFFFFFF
#define ELL 64  // ELL row stride; max degree ~45 (Binom(192000,1/12000)), P(>64)~1e-20

// acc_lo += s*(float)f16_lo(u); acc_hi += s*(float)f16_hi(u)  -- one VOP3P each
__device__ __forceinline__ void fmix2(float& lo, float& hi, unsigned u, float s) {
    asm("v_fma_mix_f32 %0, %2, %3, %0 op_sel:[0,0,0] op_sel_hi:[1,0,0]\n\t"
        "v_fma_mix_f32 %1, %2, %3, %1 op_sel:[1,0,0] op_sel_hi:[1,0,0]"
        : "+v"(lo), "+v"(hi)
        : "v"(u), "v"(s));
}

// acc += a.lo*b.lo + a.hi*b.hi  (f16 pairs, f32 accumulate) -- one VOP3P
__device__ __forceinline__ void dot2acc(float& acc, unsigned a, unsigned b) {
    asm("v_dot2_f32_f16 %0, %1, %2, %0" : "+v"(acc) : "v"(a), "v"(b));
}

__device__ __forceinline__ unsigned packh2(float lo, float hi) {
    __half2 h = __floats2half2_rn(lo, hi);
    return *reinterpret_cast<unsigned*>(&h);
}

#define ACCM(p, u)                                            \
    fmix2(p##0, p##1, u.x, one); fmix2(p##2, p##3, u.y, one); \
    fmix2(p##4, p##5, u.z, one); fmix2(p##6, p##7, u.w, one)

#define RED2(x) x += __shfl_xor(x, 16); x += __shfl_xor(x, 32)

// ---- zero deg[12288] (12 blocks * 256 * int4 = 49152 B) ----
__global__ __launch_bounds__(256) void clear_ws(int4* __restrict__ p) {
    p[blockIdx.x * 256 + threadIdx.x] = int4{0, 0, 0, 0};
}

// ---- merged: x->f16 + ELL edge scatter (blocks 0..2999) | weight fuse+pack (3000..3127) ----
__global__ __launch_bounds__(256) void prep_fuse(const float* __restrict__ x,
                                                 unsigned* __restrict__ xbu,
                                                 const int* __restrict__ ei,
                                                 int* __restrict__ deg,
                                                 int* __restrict__ col,
                                                 const float* __restrict__ W1,
                                                 const float* __restrict__ W2,
                                                 const float* __restrict__ Wg,
                                                 const float* __restrict__ b1,
                                                 const float* __restrict__ b2,
                                                 const float* __restrict__ bg,
                                                 unsigned* __restrict__ Wp1,
                                                 unsigned* __restrict__ Wp2,
                                                 unsigned* __restrict__ Wpf1,
                                                 unsigned* __restrict__ Wpf2,
                                                 float* __restrict__ bfused) {
    const int tid = threadIdx.x;
    if (blockIdx.x < 3000) {
        int g = blockIdx.x * 256 + tid;
        if (g < N_NODES * C / 2) {
            unsigned pa = __half_as_ushort(__float2half(x[2 * g]));
            unsigned pb = __half_as_ushort(__float2half(x[2 * g + 1]));
            xbu[g] = pa | (pb << 16);
        }
        if (g < NEDGE) {
            int s = ei[g];
            int t = ei[NEDGE + g];
            int pos = atomicAdd(&deg[s], 1);
            col[(s << 6) + pos] = t;
        }
        return;
    }
    __shared__ __align__(16) float wg1[C];
    __shared__ __align__(16) float wg2[C];
    __shared__ float sb[C];
    __shared__ float l1[C], l2[C], lf1[C], lf2[C];
    const int c = blockIdx.x - 3000;
    const int j = tid;
    if (j < 128) {
        float g1 = Wg[(size_t)j * C + c];
        float g2 = Wg[(size_t)(C + j) * C + c];
        wg1[j] = g1;
        wg2[j] = g2;
        sb[j] = b1[j] * g1 + b2[j] * g2;
    }
    __syncthreads();
    if (j < 128) {
        float s1 = 0.f, s2 = 0.f;
        for (int k = 0; k < C; k += 4) {
            float4 a = *(const float4*)&W1[(size_t)j * C + k];
            float4 b = *(const float4*)&W2[(size_t)j * C + k];
            float4 u = *(const float4*)&wg1[k];
            float4 v = *(const float4*)&wg2[k];
            s1 += a.x * u.x + a.y * u.y + a.z * u.z + a.w * u.w;
            s2 += b.x * v.x + b.y * v.y + b.z * v.z + b.w * v.w;
        }
        l1[j] = W1[(size_t)j * C + c];
        l2[j] = W2[(size_t)j * C + c];
        lf1[j] = s1;
        lf2[j] = s2;
    }
    __syncthreads();
    if (j < 64) {
        Wp1[(size_t)j * C + c]  = packh2(l1[2 * j], l1[2 * j + 1]);
        Wp2[(size_t)j * C + c]  = packh2(l2[2 * j], l2[2 * j + 1]);
        Wpf1[(size_t)j * C + c] = packh2(lf1[2 * j], lf1[2 * j + 1]);
        Wpf2[(size_t)j * C + c] = packh2(lf2[2 * j], lf2[2 * j + 1]);
    }
    if (j == 0) {
        float s = bg[c];
        for (int k = 0; k < C; ++k) s += sb[k];
        bfused[c] = s;
    }
}

// ---- mark dup edges (sign bit) + h(dedup, f16 out) + agg1(multiplicity, fp32 out) ----
__global__ __launch_bounds__(256) void markdup_h(const int* __restrict__ deg,
                                                 int* __restrict__ col,
                                                 const unsigned* __restrict__ xb,
                                                 unsigned* __restrict__ hb,
                                                 float* __restrict__ agg1) {
    __shared__ int rows[4][ELL];
    const int tid = threadIdx.x;
    const int lane = tid & 63, wv = tid >> 6;
    const int i = blockIdx.x * 4 + wv;
    const int rb = i << 6;
    const int d = deg[i];
    const uint4* xb4 = (const uint4*)xb;
    const float one = 1.0f;

    if (lane < d) rows[wv][lane] = col[rb + lane];
    if (lane < d) {
        int vm = rows[wv][lane] & MSK;
        bool dup = false;
        for (int e2 = 0; e2 < lane; ++e2)
            if ((rows[wv][e2] & MSK) == vm) { dup = true; break; }
        if (dup) {
            rows[wv][lane] = vm | 0x80000000;
            col[rb + lane] = vm | 0x80000000;   // visible to next dispatch
        }
    }
    __syncthreads();

    const int g = lane >> 4, l16 = lane & 15;
    float a0 = 0, a1 = 0, a2 = 0, a3 = 0, a4 = 0, a5 = 0, a6 = 0, a7 = 0;
    float b0 = 0, b1 = 0, b2 = 0, b3 = 0, b4 = 0, b5 = 0, b6 = 0, b7 = 0;
    for (int e = g; e < d; e += 4) {
        int c0 = rows[wv][e];
        int k = c0 & MSK;
        uint4 u = xb4[(unsigned)((k << 4) | l16)];
        ACCM(b, u);
        if (c0 >= 0) { ACCM(a, u); }
    }
    RED2(a0); RED2(a1); RED2(a2); RED2(a3); RED2(a4); RED2(a5); RED2(a6); RED2(a7);
    RED2(b0); RED2(b1); RED2(b2); RED2(b3); RED2(b4); RED2(b5); RED2(b6); RED2(b7);
    if (lane < 16) {
        uint4 hp = {packh2(a0, a1), packh2(a2, a3), packh2(a4, a5), packh2(a6, a7)};
        ((uint4*)hb)[(unsigned)((i << 4) | l16)] = hp;
        float4 w0 = {b0, b1, b2, b3}, w1 = {b4, b5, b6, b7};
        *(float4*)&agg1[(size_t)i * C + l16 * 8] = w0;
        *(float4*)&agg1[(size_t)i * C + l16 * 8 + 4] = w1;
    }
}

// ---- wave-per-node: union + corrections + agg2 = Adj_bin@h - corrections.
//      ZERO barriers. All __shfl in exec-uniform code (R19 bug fixed). ----
__global__ __launch_bounds__(256) void twohop_fused(const int* __restrict__ deg,
                                                    const int* __restrict__ col,
                                                    const unsigned* __restrict__ xb,
                                                    const unsigned* __restrict__ hb,
                                                    float* __restrict__ agg2) {
    __shared__ unsigned accS[4][BW];          // 6 KB: per-wave dedup bitset
    __shared__ int jrowS[4][64];              // 1 KB: per-wave row cache
    __shared__ unsigned short corrS[4][128];  // 1 KB: per-wave corrections
    __shared__ int ncS[4];
    const int tid = threadIdx.x;
    const int lane = tid & 63, wv = tid >> 6;
    const int i = blockIdx.x * 4 + wv;
    unsigned* acc = accS[wv];
    unsigned short* corr = corrS[wv];
    const int rb = i << 6;
    const int d = deg[i];
    const uint4* xb4 = (const uint4*)xb;
    const uint4* hb4 = (const uint4*)hb;
    const float one = 1.0f, neg1 = -1.0f;

#pragma unroll
    for (int m = 0; m < 6; ++m) acc[lane + (m << 6)] = 0u;
    if (lane == 0) ncS[wv] = 0;

    // own row entry + neighbor row length (0 for dup-marked -> never selected by search)
    int j = -1, len = 0;
    if (lane < d) {
        j = col[rb + lane];
        if (j >= 0) len = deg[j];
    }
    jrowS[wv][lane] = j;                   // LDS cache: divergence-safe reads later
    const int jb = (j >= 0) ? (j << 6) : 0;
    int p = len;
#pragma unroll
    for (int dd = 1; dd < 64; dd <<= 1) {
        int u = __shfl_up(p, dd);
        if (lane >= dd) p += u;
    }
    const int myPos = p - len;             // exclusive prefix
    const int total = __shfl(p, 63);

    // flattened candidates: UNIFORM trip count; all lanes execute every shfl
    for (int q0 = 0; q0 < total; q0 += 64) {
        const int q = q0 + lane;
        const int qc = (q < total) ? q : (total - 1);  // clamped: search stays valid
        int lo = 0, hi = d - 1;
#pragma unroll
        for (int it = 0; it < 6; ++it) {
            int mid = (lo + hi + 1) >> 1;
            int sp = __shfl(myPos, mid);
            if (lo < hi) { if (sp <= qc) lo = mid; else hi = mid - 1; }
        }
        const int base = __shfl(jb, lo);
        const int pos0 = __shfl(myPos, lo);
        if (q < total) {
            int t = col[base + (qc - pos0)];
            if (t >= 0) {                   // skip marked entries in j's row
                unsigned bit = 1u << (t & 31);
                unsigned old = atomicOr(&acc[t >> 5], bit);
                if (old & bit) {            // duplicate 2-path: correction
                    int pc = atomicAdd(&ncS[wv], 1);
                    if (pc < 128) corr[pc] = (unsigned short)t;
                }
            }
        }
    }
    // diagonal: if i reachable in 2 hops, subtract its remaining copy
    if (lane == 0) {
        if (acc[i >> 5] & (1u << (i & 31))) {
            int pc = atomicAdd(&ncS[wv], 1);
            if (pc < 128) corr[pc] = (unsigned short)i;
        }
    }

    // t = Adj_bin @ h: gather f16 h rows over unmarked entries (indices from LDS)
    const int g = lane >> 4, l16 = lane & 15;
    float a0 = 0, a1 = 0, a2 = 0, a3 = 0, a4 = 0, a5 = 0, a6 = 0, a7 = 0;
    for (int e = g; e < d; e += 4) {
        int t = jrowS[wv][e];
        if (t >= 0) {
            uint4 u = hb4[(unsigned)((t << 4) | l16)];
            ACCM(a, u);
        }
    }

    // corrections: subtract x_t for each extra 2-path occurrence
    {
        int nc = ncS[wv];
        if (nc > 128) nc = 128;
        for (int q = g; q < nc; q += 4) {
            int t = corr[q];
            uint4 u = xb4[(unsigned)((t << 4) | l16)];
            fmix2(a0, a1, u.x, neg1);
            fmix2(a2, a3, u.y, neg1);
            fmix2(a4, a5, u.z, neg1);
            fmix2(a6, a7, u.w, neg1);
        }
    }

    RED2(a0); RED2(a1); RED2(a2); RED2(a3); RED2(a4); RED2(a5); RED2(a6); RED2(a7);
    if (lane < 16) {
        float4 w0 = {a0, a1, a2, a3}, w1 = {a4, a5, a6, a7};
        *(float4*)&agg2[(size_t)i * C + l16 * 8] = w0;
        *(float4*)&agg2[(size_t)i * C + l16 * 8 + 4] = w1;
    }
}

// ---- single-pass epilogue: 16 rows/block (750 blocks), f16 k-pair dot2 ----
__global__ __launch_bounds__(256) void epilogue(const float* __restrict__ agg1,
                                                const float* __restrict__ agg2,
                                                const unsigned* __restrict__ Wp1,
                                                const unsigned* __restrict__ Wp2,
                                                const unsigned* __restrict__ Wpf1,
                                                const unsigned* __restrict__ Wpf2,
                                                const float* __restrict__ b1,
                                                const float* __restrict__ b2,
                                                const float* __restrict__ bfused,
                                                float* __restrict__ out) {
    __shared__ unsigned shA[16][64];
    __shared__ unsigned shB[16][64];
    const int r0 = blockIdx.x * 16;
    const int tid = threadIdx.x;
    const int c0 = (tid & 63) * 2;
    const int rg = (tid >> 6) * 4;

    for (int idx = tid; idx < 512; idx += 256) {
        int r = idx >> 5, q = idx & 31;
        float4 fa = *(const float4*)&agg1[(size_t)(r0 + r) * C + q * 4];
        float4 fb = *(const float4*)&agg2[(size_t)(r0 + r) * C + q * 4];
        uint2 ua = {packh2(fa.x, fa.y), packh2(fa.z, fa.w)};
        uint2 ub = {packh2(fb.x, fb.y), packh2(fb.z, fb.w)};
        *(uint2*)&shA[r][q * 2] = ua;
        *(uint2*)&shB[r][q * 2] = ub;
    }
    __syncthreads();

    float z1v[4][2] = {}, z2v[4][2] = {}, gv[4][2] = {};
    for (int t = 0; t < 32; ++t) {
        const int k2 = t * 2;
        uint2 w1a = *(const uint2*)&Wp1[(size_t)k2 * C + c0];
        uint2 w1b = *(const uint2*)&Wp1[(size_t)(k2 + 1) * C + c0];
        uint2 w2a = *(const uint2*)&Wp2[(size_t)k2 * C + c0];
        uint2 w2b = *(const uint2*)&Wp2[(size_t)(k2 + 1) * C + c0];
        uint2 f1a = *(const uint2*)&Wpf1[(size_t)k2 * C + c0];
        uint2 f1b = *(const uint2*)&Wpf1[(size_t)(k2 + 1) * C + c0];
        uint2 f2a = *(const uint2*)&Wpf2[(size_t)k2 * C + c0];
        uint2 f2b = *(const uint2*)&Wpf2[(size_t)(k2 + 1) * C + c0];
#pragma unroll
        for (int r = 0; r < 4; ++r) {
            uint2 aA = *(const uint2*)&shA[rg + r][k2];
            uint2 aB = *(const uint2*)&shB[rg + r][k2];
            dot2acc(z1v[r][0], aA.x, w1a.x); dot2acc(z1v[r][0], aA.y, w1b.x);
            dot2acc(z1v[r][1], aA.x, w1a.y); dot2acc(z1v[r][1], aA.y, w1b.y);
            dot2acc(z2v[r][0], aB.x, w2a.x); dot2acc(z2v[r][0], aB.y, w2b.x);
            dot2acc(z2v[r][1], aB.x, w2a.y); dot2acc(z2v[r][1], aB.y, w2b.y);
            dot2acc(gv[r][0], aA.x, f1a.x);  dot2acc(gv[r][0], aA.y, f1b.x);
            dot2acc(gv[r][1], aA.x, f1a.y);  dot2acc(gv[r][1], aA.y, f1b.y);
            dot2acc(gv[r][0], aB.x, f2a.x);  dot2acc(gv[r][0], aB.y, f2b.x);
            dot2acc(gv[r][1], aB.x, f2a.y);  dot2acc(gv[r][1], aB.y, f2b.y);
        }
    }
    const float2 b1v = *(const float2*)&b1[c0];
    const float2 b2v = *(const float2*)&b2[c0];
    const float2 bfv = *(const float2*)&bfused[c0];
#pragma unroll
    for (int r = 0; r < 4; ++r) {
        float g0 = 1.f / (1.f + expf(-(gv[r][0] + bfv.x)));
        float g1 = 1.f / (1.f + expf(-(gv[r][1] + bfv.y)));
        float2 res;
        res.x = g0 * (z1v[r][0] + b1v.x) + (1.f - g0) * (z2v[r][0] + b2v.x);
        res.y = g1 * (z1v[r][1] + b1v.y) + (1.f - g1) * (z2v[r][1] + b2v.y);
        *(float2*)&out[(size_t)(r0 + rg + r) * C + c0] = res;
    }
}

extern "C" void kernel_launch(void* const* d_in, const int* in_sizes, int n_in,
                              void* d_out, int out_size, void* d_ws, size_t ws_size,
                              hipStream_t stream) {
    const float* x  = (const float*)d_in[0];
    const int*   ei = (const int*)d_in[1];
    const float* W1 = (const float*)d_in[2];
    const float* b1 = (const float*)d_in[3];
    const float* W2 = (const float*)d_in[4];
    const float* b2 = (const float*)d_in[5];
    const float* Wg = (const float*)d_in[6];
    const float* bg = (const float*)d_in[7];
    float* out = (float*)d_out;

    char* ws = (char*)d_ws;
    size_t o = 0;
    auto alloc = [&](size_t bytes) { char* p = ws + o; o = (o + bytes + 255) & ~(size_t)255; return p; };
    int* col      = (int*)alloc((size_t)N_NODES * ELL * 4);     // 3 MB ELL
    int* deg      = (int*)alloc((size_t)12288 * 4);             // cleared region (49152 B)
    unsigned* xb  = (unsigned*)alloc((size_t)N_NODES * C * 2);  // f16 x
    unsigned* hb  = (unsigned*)alloc((size_t)N_NODES * C * 2);  // f16 h = Adj_bin@x
    float* agg1   = (float*)alloc((size_t)N_NODES * C * 4);
    float* agg2   = (float*)alloc((size_t)N_NODES * C * 4);
    unsigned* Wp1  = (unsigned*)alloc((size_t)(C / 2) * C * 4);
    unsigned* Wp2  = (unsigned*)alloc((size_t)(C / 2) * C * 4);
    unsigned* Wpf1 = (unsigned*)alloc((size_t)(C / 2) * C * 4);
    unsigned* Wpf2 = (unsigned*)alloc((size_t)(C / 2) * C * 4);
    float* bfused  = (float*)alloc((size_t)C * 4);
    // total ~21.7 MB (proven safe)

    clear_ws<<<12, 256, 0, stream>>>((int4*)deg);  // 12*256*16B = 49152 B >= 12288 ints
    prep_fuse<<<3128, 256, 0, stream>>>(x, xb, ei, deg, col, W1, W2, Wg, b1, b2, bg,
                                        Wp1, Wp2, Wpf1, Wpf2, bfused);
    markdup_h<<<N_NODES / 4, 256, 0, stream>>>(deg, col, xb, hb, agg1);
    twohop_fused<<<N_NODES / 4, 256, 0, stream>>>(deg, col, xb, hb, agg2);
    epilogue<<<N_NODES / 16, 256, 0, stream>>>(agg1, agg2, Wp1, Wp2, Wpf1, Wpf2,
                                               b1, b2, bfused, out);
}

// Round 21
// 94.874 us; speedup vs baseline: 2.1730x; 1.0889x over previous
//
#include <hip/hip_runtime.h>
#include <hip/hip_fp16.h>
#include <math.h>

#define N_NODES 12000
#define C 128
#define NEDGE 192000
#define BW 384  // u32 words per dedup bitset (12288 bits >= 12000)
#define MSK 0x7FFFFFFF
#define ELL 64  // ELL row stride; max degree ~45 (Binom(192000,1/12000)), P(>64)~1e-20

// acc_lo += s*(float)f16_lo(u); acc_hi += s*(float)f16_hi(u)  -- one VOP3P each
__device__ __forceinline__ void fmix2(float& lo, float& hi, unsigned u, float s) {
    asm("v_fma_mix_f32 %0, %2, %3, %0 op_sel:[0,0,0] op_sel_hi:[1,0,0]\n\t"
        "v_fma_mix_f32 %1, %2, %3, %1 op_sel:[1,0,0] op_sel_hi:[1,0,0]"
        : "+v"(lo), "+v"(hi)
        : "v"(u), "v"(s));
}

// acc += a.lo*b.lo + a.hi*b.hi  (f16 pairs, f32 accumulate) -- one VOP3P
__device__ __forceinline__ void dot2acc(float& acc, unsigned a, unsigned b) {
    asm("v_dot2_f32_f16 %0, %1, %2, %0" : "+v"(acc) : "v"(a), "v"(b));
}

__device__ __forceinline__ unsigned packh2(float lo, float hi) {
    __half2 h = __floats2half2_rn(lo, hi);
    return *reinterpret_cast<unsigned*>(&h);
}

#define ACCM(p, u)                                            \
    fmix2(p##0, p##1, u.x, one); fmix2(p##2, p##3, u.y, one); \
    fmix2(p##4, p##5, u.z, one); fmix2(p##6, p##7, u.w, one)

#define RED2(x) x += __shfl_xor(x, 16); x += __shfl_xor(x, 32)

// ---- zero deg[12288] (12 blocks * 256 * int4 = 49152 B) ----
__global__ __launch_bounds__(256) void clear_ws(int4* __restrict__ p) {
    p[blockIdx.x * 256 + threadIdx.x] = int4{0, 0, 0, 0};
}

// ---- merged: x->f16 + ELL edge scatter (blocks 0..2999) | weight fuse+pack (3000..3127) ----
// Weight layout Wq*: [t][c*2+u] where t = pair-of-kpairs, u = kpair within pair.
// uint4 at (t*256 + c0*2) = { (k2,c0), (k2+1,c0), (k2,c0+1), (k2+1,c0+1) }, k2 = 2t.
__global__ __launch_bounds__(256) void prep_fuse(const float* __restrict__ x,
                                                 unsigned* __restrict__ xbu,
                                                 const int* __restrict__ ei,
                                                 int* __restrict__ deg,
                                                 int* __restrict__ col,
                                                 const float* __restrict__ W1,
                                                 const float* __restrict__ W2,
                                                 const float* __restrict__ Wg,
                                                 const float* __restrict__ b1,
                                                 const float* __restrict__ b2,
                                                 const float* __restrict__ bg,
                                                 unsigned* __restrict__ Wq1,
                                                 unsigned* __restrict__ Wq2,
                                                 unsigned* __restrict__ Wqf1,
                                                 unsigned* __restrict__ Wqf2,
                                                 float* __restrict__ bfused) {
    const int tid = threadIdx.x;
    if (blockIdx.x < 3000) {
        int g = blockIdx.x * 256 + tid;
        if (g < N_NODES * C / 2) {
            unsigned pa = __half_as_ushort(__float2half(x[2 * g]));
            unsigned pb = __half_as_ushort(__float2half(x[2 * g + 1]));
            xbu[g] = pa | (pb << 16);
        }
        if (g < NEDGE) {
            int s = ei[g];
            int t = ei[NEDGE + g];
            int pos = atomicAdd(&deg[s], 1);
            col[(s << 6) + pos] = t;
        }
        return;
    }
    __shared__ __align__(16) float wg1[C];
    __shared__ __align__(16) float wg2[C];
    __shared__ float sb[C];
    __shared__ float l1[C], l2[C], lf1[C], lf2[C];
    const int c = blockIdx.x - 3000;
    const int j = tid;
    if (j < 128) {
        float g1 = Wg[(size_t)j * C + c];
        float g2 = Wg[(size_t)(C + j) * C + c];
        wg1[j] = g1;
        wg2[j] = g2;
        sb[j] = b1[j] * g1 + b2[j] * g2;
    }
    __syncthreads();
    if (j < 128) {
        float s1 = 0.f, s2 = 0.f;
        for (int k = 0; k < C; k += 4) {
            float4 a = *(const float4*)&W1[(size_t)j * C + k];
            float4 b = *(const float4*)&W2[(size_t)j * C + k];
            float4 u = *(const float4*)&wg1[k];
            float4 v = *(const float4*)&wg2[k];
            s1 += a.x * u.x + a.y * u.y + a.z * u.z + a.w * u.w;
            s2 += b.x * v.x + b.y * v.y + b.z * v.z + b.w * v.w;
        }
        l1[j] = W1[(size_t)j * C + c];
        l2[j] = W2[(size_t)j * C + c];
        lf1[j] = s1;
        lf2[j] = s2;
    }
    __syncthreads();
    if (j < 64) {   // j = k-pair index; t = j>>1 groups two k-pairs, u = j&1
        const int t = j >> 1, u = j & 1;
        const int o = t * 256 + c * 2 + u;
        Wq1[o]  = packh2(l1[2 * j], l1[2 * j + 1]);
        Wq2[o]  = packh2(l2[2 * j], l2[2 * j + 1]);
        Wqf1[o] = packh2(lf1[2 * j], lf1[2 * j + 1]);
        Wqf2[o] = packh2(lf2[2 * j], lf2[2 * j + 1]);
    }
    if (j == 0) {
        float s = bg[c];
        for (int k = 0; k < C; ++k) s += sb[k];
        bfused[c] = s;
    }
}

// ---- mark dup edges (sign bit) + h(dedup, f16) + agg1(multiplicity, f16 packed) ----
__global__ __launch_bounds__(256) void markdup_h(const int* __restrict__ deg,
                                                 int* __restrict__ col,
                                                 const unsigned* __restrict__ xb,
                                                 unsigned* __restrict__ hb,
                                                 unsigned* __restrict__ agg1p) {
    __shared__ int rows[4][ELL];
    const int tid = threadIdx.x;
    const int lane = tid & 63, wv = tid >> 6;
    const int i = blockIdx.x * 4 + wv;
    const int rb = i << 6;
    const int d = deg[i];
    const uint4* xb4 = (const uint4*)xb;
    const float one = 1.0f;

    if (lane < d) rows[wv][lane] = col[rb + lane];
    if (lane < d) {
        int vm = rows[wv][lane] & MSK;
        bool dup = false;
        for (int e2 = 0; e2 < lane; ++e2)
            if ((rows[wv][e2] & MSK) == vm) { dup = true; break; }
        if (dup) {
            rows[wv][lane] = vm | 0x80000000;
            col[rb + lane] = vm | 0x80000000;   // visible to next dispatch
        }
    }
    __syncthreads();

    const int g = lane >> 4, l16 = lane & 15;
    float a0 = 0, a1 = 0, a2 = 0, a3 = 0, a4 = 0, a5 = 0, a6 = 0, a7 = 0;
    float b0 = 0, b1 = 0, b2 = 0, b3 = 0, b4 = 0, b5 = 0, b6 = 0, b7 = 0;
    for (int e = g; e < d; e += 4) {
        int c0 = rows[wv][e];
        int k = c0 & MSK;
        uint4 u = xb4[(unsigned)((k << 4) | l16)];
        ACCM(b, u);
        if (c0 >= 0) { ACCM(a, u); }
    }
    RED2(a0); RED2(a1); RED2(a2); RED2(a3); RED2(a4); RED2(a5); RED2(a6); RED2(a7);
    RED2(b0); RED2(b1); RED2(b2); RED2(b3); RED2(b4); RED2(b5); RED2(b6); RED2(b7);
    if (lane < 16) {
        uint4 hp = {packh2(a0, a1), packh2(a2, a3), packh2(a4, a5), packh2(a6, a7)};
        ((uint4*)hb)[(unsigned)((i << 4) | l16)] = hp;
        uint4 ap = {packh2(b0, b1), packh2(b2, b3), packh2(b4, b5), packh2(b6, b7)};
        ((uint4*)agg1p)[(unsigned)((i << 4) | l16)] = ap;
    }
}

// ---- wave-per-node: union + corrections + agg2(f16 packed) = Adj_bin@h - corr. ----
__global__ __launch_bounds__(256) void twohop_fused(const int* __restrict__ deg,
                                                    const int* __restrict__ col,
                                                    const unsigned* __restrict__ xb,
                                                    const unsigned* __restrict__ hb,
                                                    unsigned* __restrict__ agg2p) {
    __shared__ unsigned accS[4][BW];          // 6 KB: per-wave dedup bitset
    __shared__ int jrowS[4][64];              // 1 KB: per-wave row cache
    __shared__ unsigned short corrS[4][128];  // 1 KB: per-wave corrections
    __shared__ int ncS[4];
    const int tid = threadIdx.x;
    const int lane = tid & 63, wv = tid >> 6;
    const int i = blockIdx.x * 4 + wv;
    unsigned* acc = accS[wv];
    unsigned short* corr = corrS[wv];
    const int rb = i << 6;
    const int d = deg[i];
    const uint4* xb4 = (const uint4*)xb;
    const uint4* hb4 = (const uint4*)hb;
    const float one = 1.0f, neg1 = -1.0f;

#pragma unroll
    for (int m = 0; m < 6; ++m) acc[lane + (m << 6)] = 0u;
    if (lane == 0) ncS[wv] = 0;

    int j = -1, len = 0;
    if (lane < d) {
        j = col[rb + lane];
        if (j >= 0) len = deg[j];
    }
    jrowS[wv][lane] = j;                   // LDS cache: divergence-safe reads later
    const int jb = (j >= 0) ? (j << 6) : 0;
    int p = len;
#pragma unroll
    for (int dd = 1; dd < 64; dd <<= 1) {
        int u = __shfl_up(p, dd);
        if (lane >= dd) p += u;
    }
    const int myPos = p - len;
    const int total = __shfl(p, 63);

    // flattened candidates: UNIFORM trip count; all lanes execute every shfl
    for (int q0 = 0; q0 < total; q0 += 64) {
        const int q = q0 + lane;
        const int qc = (q < total) ? q : (total - 1);
        int lo = 0, hi = d - 1;
#pragma unroll
        for (int it = 0; it < 6; ++it) {
            int mid = (lo + hi + 1) >> 1;
            int sp = __shfl(myPos, mid);
            if (lo < hi) { if (sp <= qc) lo = mid; else hi = mid - 1; }
        }
        const int base = __shfl(jb, lo);
        const int pos0 = __shfl(myPos, lo);
        if (q < total) {
            int t = col[base + (qc - pos0)];
            if (t >= 0) {
                unsigned bit = 1u << (t & 31);
                unsigned old = atomicOr(&acc[t >> 5], bit);
                if (old & bit) {
                    int pc = atomicAdd(&ncS[wv], 1);
                    if (pc < 128) corr[pc] = (unsigned short)t;
                }
            }
        }
    }
    if (lane == 0) {
        if (acc[i >> 5] & (1u << (i & 31))) {
            int pc = atomicAdd(&ncS[wv], 1);
            if (pc < 128) corr[pc] = (unsigned short)i;
        }
    }

    const int g = lane >> 4, l16 = lane & 15;
    float a0 = 0, a1 = 0, a2 = 0, a3 = 0, a4 = 0, a5 = 0, a6 = 0, a7 = 0;
    for (int e = g; e < d; e += 4) {
        int t = jrowS[wv][e];
        if (t >= 0) {
            uint4 u = hb4[(unsigned)((t << 4) | l16)];
            ACCM(a, u);
        }
    }

    {
        int nc = ncS[wv];
        if (nc > 128) nc = 128;
        for (int q = g; q < nc; q += 4) {
            int t = corr[q];
            uint4 u = xb4[(unsigned)((t << 4) | l16)];
            fmix2(a0, a1, u.x, neg1);
            fmix2(a2, a3, u.y, neg1);
            fmix2(a4, a5, u.z, neg1);
            fmix2(a6, a7, u.w, neg1);
        }
    }

    RED2(a0); RED2(a1); RED2(a2); RED2(a3); RED2(a4); RED2(a5); RED2(a6); RED2(a7);
    if (lane < 16) {
        uint4 ap = {packh2(a0, a1), packh2(a2, a3), packh2(a4, a5), packh2(a6, a7)};
        ((uint4*)agg2p)[(unsigned)((i << 4) | l16)] = ap;
    }
}

// ---- single-pass epilogue: 16 rows/block, packed agg staging + uint4 weight loads ----
__global__ __launch_bounds__(256) void epilogue(const unsigned* __restrict__ agg1p,
                                                const unsigned* __restrict__ agg2p,
                                                const unsigned* __restrict__ Wq1,
                                                const unsigned* __restrict__ Wq2,
                                                const unsigned* __restrict__ Wqf1,
                                                const unsigned* __restrict__ Wqf2,
                                                const float* __restrict__ b1,
                                                const float* __restrict__ b2,
                                                const float* __restrict__ bfused,
                                                float* __restrict__ out) {
    __shared__ unsigned shA[16][64];
    __shared__ unsigned shB[16][64];
    const int r0 = blockIdx.x * 16;
    const int tid = threadIdx.x;
    const int c0 = (tid & 63) * 2;
    const int rg = (tid >> 6) * 4;

    {   // 16 rows x 16 uint4 = 256: one per thread, straight copy (agg already f16)
        const int r = tid >> 4, q4 = tid & 15;
        ((uint4*)shA[r])[q4] = ((const uint4*)agg1p)[(unsigned)(((r0 + r) << 4) | q4)];
        ((uint4*)shB[r])[q4] = ((const uint4*)agg2p)[(unsigned)(((r0 + r) << 4) | q4)];
    }
    __syncthreads();

    float z1v[4][2] = {}, z2v[4][2] = {}, gv[4][2] = {};
    const int wbase = c0 * 2;
    for (int t = 0; t < 32; ++t) {
        uint4 W1q = *(const uint4*)&Wq1[t * 256 + wbase];   // {k2|c0, k2+1|c0, k2|c0+1, k2+1|c0+1}
        uint4 W2q = *(const uint4*)&Wq2[t * 256 + wbase];
        uint4 F1q = *(const uint4*)&Wqf1[t * 256 + wbase];
        uint4 F2q = *(const uint4*)&Wqf2[t * 256 + wbase];
        const int k2 = t * 2;
#pragma unroll
        for (int r = 0; r < 4; ++r) {
            uint2 aA = *(const uint2*)&shA[rg + r][k2];
            uint2 aB = *(const uint2*)&shB[rg + r][k2];
            dot2acc(z1v[r][0], aA.x, W1q.x); dot2acc(z1v[r][0], aA.y, W1q.y);
            dot2acc(z1v[r][1], aA.x, W1q.z); dot2acc(z1v[r][1], aA.y, W1q.w);
            dot2acc(z2v[r][0], aB.x, W2q.x); dot2acc(z2v[r][0], aB.y, W2q.y);
            dot2acc(z2v[r][1], aB.x, W2q.z); dot2acc(z2v[r][1], aB.y, W2q.w);
            dot2acc(gv[r][0], aA.x, F1q.x);  dot2acc(gv[r][0], aA.y, F1q.y);
            dot2acc(gv[r][1], aA.x, F1q.z);  dot2acc(gv[r][1], aA.y, F1q.w);
            dot2acc(gv[r][0], aB.x, F2q.x);  dot2acc(gv[r][0], aB.y, F2q.y);
            dot2acc(gv[r][1], aB.x, F2q.z);  dot2acc(gv[r][1], aB.y, F2q.w);
        }
    }
    const float2 b1v = *(const float2*)&b1[c0];
    const float2 b2v = *(const float2*)&b2[c0];
    const float2 bfv = *(const float2*)&bfused[c0];
#pragma unroll
    for (int r = 0; r < 4; ++r) {
        float g0 = 1.f / (1.f + expf(-(gv[r][0] + bfv.x)));
        float g1 = 1.f / (1.f + expf(-(gv[r][1] + bfv.y)));
        float2 res;
        res.x = g0 * (z1v[r][0] + b1v.x) + (1.f - g0) * (z2v[r][0] + b2v.x);
        res.y = g1 * (z1v[r][1] + b1v.y) + (1.f - g1) * (z2v[r][1] + b2v.y);
        *(float2*)&out[(size_t)(r0 + rg + r) * C + c0] = res;
    }
}

extern "C" void kernel_launch(void* const* d_in, const int* in_sizes, int n_in,
                              void* d_out, int out_size, void* d_ws, size_t ws_size,
                              hipStream_t stream) {
    const float* x  = (const float*)d_in[0];
    const int*   ei = (const int*)d_in[1];
    const float* W1 = (const float*)d_in[2];
    const float* b1 = (const float*)d_in[3];
    const float* W2 = (const float*)d_in[4];
    const float* b2 = (const float*)d_in[5];
    const float* Wg = (const float*)d_in[6];
    const float* bg = (const float*)d_in[7];
    float* out = (float*)d_out;

    char* ws = (char*)d_ws;
    size_t o = 0;
    auto alloc = [&](size_t bytes) { char* p = ws + o; o = (o + bytes + 255) & ~(size_t)255; return p; };
    int* col      = (int*)alloc((size_t)N_NODES * ELL * 4);       // 3 MB ELL
    int* deg      = (int*)alloc((size_t)12288 * 4);               // cleared region (49152 B)
    unsigned* xb  = (unsigned*)alloc((size_t)N_NODES * C * 2);    // f16 x
    unsigned* hb  = (unsigned*)alloc((size_t)N_NODES * C * 2);    // f16 h = Adj_bin@x
    unsigned* agg1p = (unsigned*)alloc((size_t)N_NODES * C * 2);  // f16 packed agg1
    unsigned* agg2p = (unsigned*)alloc((size_t)N_NODES * C * 2);  // f16 packed agg2
    unsigned* Wq1  = (unsigned*)alloc((size_t)(C / 2) * C * 4);
    unsigned* Wq2  = (unsigned*)alloc((size_t)(C / 2) * C * 4);
    unsigned* Wqf1 = (unsigned*)alloc((size_t)(C / 2) * C * 4);
    unsigned* Wqf2 = (unsigned*)alloc((size_t)(C / 2) * C * 4);
    float* bfused  = (float*)alloc((size_t)C * 4);
    // total ~15.7 MB (proven safe)

    clear_ws<<<12, 256, 0, stream>>>((int4*)deg);
    prep_fuse<<<3128, 256, 0, stream>>>(x, xb, ei, deg, col, W1, W2, Wg, b1, b2, bg,
                                        Wq1, Wq2, Wqf1, Wqf2, bfused);
    markdup_h<<<N_NODES / 4, 256, 0, stream>>>(deg, col, xb, hb, agg1p);
    twohop_fused<<<N_NODES / 4, 256, 0, stream>>>(deg, col, xb, hb, agg2p);
    epilogue<<<N_NODES / 16, 256, 0, stream>>>(agg1p, agg2p, Wq1, Wq2, Wqf1, Wqf2,
                                               b1, b2, bfused, out);
}